// Round 1
// baseline (1374.964 us; speedup 1.0000x reference)
//
#include <hip/hip_runtime.h>
#include <math.h>

#define H_DIM 128
#define OUT_DIM 10

// ---------------------------------------------------------------------------
// deg[col[e]] += 1  (self-loop +1 folded into dinv_kernel)
__global__ __launch_bounds__(256) void deg_kernel(const int* __restrict__ col,
                                                  float* __restrict__ deg, int E) {
    int e = blockIdx.x * 256 + threadIdx.x;
    if (e < E) atomicAdd(&deg[col[e]], 1.0f);
}

__global__ __launch_bounds__(256) void dinv_kernel(float* __restrict__ deg, int N) {
    int n = blockIdx.x * 256 + threadIdx.x;
    if (n < N) deg[n] = rsqrtf(deg[n] + 1.0f);   // deg>=1 always (self loops)
}

// ---------------------------------------------------------------------------
// Y[N,128] = X[N,128] @ W[128,128].  W staged in LDS (64 KB).
// 16 nodes/block, 256 threads: thread = (ng 0..7, colchunk 0..31), 2 nodes/thread.
__global__ __launch_bounds__(256) void gemm_x_w(const float* __restrict__ X,
                                                const float* __restrict__ W,
                                                float* __restrict__ Y, int N) {
    __shared__ float sW[H_DIM * H_DIM];
    float4* sW4 = (float4*)sW;
    const float4* W4 = (const float4*)W;
    for (int i = threadIdx.x; i < H_DIM * H_DIM / 4; i += 256) sW4[i] = W4[i];
    __syncthreads();

    int c  = threadIdx.x & 31;   // float4 column chunk: cols 4c..4c+3
    int ng = threadIdx.x >> 5;   // 0..7
    int n0 = blockIdx.x * 16 + ng;
    int n1 = n0 + 8;
    bool v0 = n0 < N, v1 = n1 < N;
    const float* x0 = X + (size_t)n0 * H_DIM;
    const float* x1 = X + (size_t)n1 * H_DIM;

    float4 acc0 = {0.f, 0.f, 0.f, 0.f};
    float4 acc1 = {0.f, 0.f, 0.f, 0.f};
    for (int k = 0; k < H_DIM; ++k) {
        float4 w = sW4[k * 32 + c];
        float a0 = v0 ? x0[k] : 0.0f;
        float a1 = v1 ? x1[k] : 0.0f;
        acc0.x += a0 * w.x; acc0.y += a0 * w.y; acc0.z += a0 * w.z; acc0.w += a0 * w.w;
        acc1.x += a1 * w.x; acc1.y += a1 * w.y; acc1.z += a1 * w.z; acc1.w += a1 * w.w;
    }
    if (v0) ((float4*)(Y + (size_t)n0 * H_DIM))[c] = acc0;
    if (v1) ((float4*)(Y + (size_t)n1 * H_DIM))[c] = acc1;
}

// ---------------------------------------------------------------------------
// out[col[e], :] += XW[row[e], :] * dinv[row]*dinv[col]
// 64 lanes per edge, 2 floats/lane (float2 gather, 2 scalar atomics).
__global__ __launch_bounds__(256) void agg_edges(const float* __restrict__ XW,
                                                 const float* __restrict__ dinv,
                                                 const int* __restrict__ row,
                                                 const int* __restrict__ col,
                                                 float* __restrict__ out, int E) {
    int gid  = blockIdx.x * 256 + threadIdx.x;
    int e    = gid >> 6;   // wave-uniform
    int lane = gid & 63;
    if (e >= E) return;
    int r = row[e], c = col[e];
    float s = dinv[r] * dinv[c];
    float2 v = ((const float2*)(XW + (size_t)r * H_DIM))[lane];
    float* dst = out + (size_t)c * H_DIM + 2 * lane;
    atomicAdd(dst,     v.x * s);
    atomicAdd(dst + 1, v.y * s);
}

// ---------------------------------------------------------------------------
// HOUT[n,:] = relu(HOUT[n,:] + XW[n,:]*dinv[n]^2 + bias)   (in place, no atomics)
__global__ __launch_bounds__(256) void self_bias_relu(const float* __restrict__ XW,
                                                      const float* __restrict__ dinv,
                                                      const float* __restrict__ bias,
                                                      float* __restrict__ HOUT, int N) {
    int gid = blockIdx.x * 256 + threadIdx.x;
    int n = gid >> 5;
    int c = gid & 31;
    if (n >= N) return;
    float d = dinv[n];
    float s = d * d;
    float4 xv = ((const float4*)(XW   + (size_t)n * H_DIM))[c];
    float4 av = ((const float4*)(HOUT + (size_t)n * H_DIM))[c];
    float4 bv = ((const float4*)bias)[c];
    float4 r;
    r.x = fmaxf(av.x + xv.x * s + bv.x, 0.f);
    r.y = fmaxf(av.y + xv.y * s + bv.y, 0.f);
    r.z = fmaxf(av.z + xv.z * s + bv.z, 0.f);
    r.w = fmaxf(av.w + xv.w * s + bv.w, 0.f);
    ((float4*)(HOUT + (size_t)n * H_DIM))[c] = r;
}

// ---------------------------------------------------------------------------
// Mean pool per graph.  batch is sorted -> binary-search the segment bounds.
__global__ __launch_bounds__(128) void pool_kernel(const float* __restrict__ Hin,
                                                   const int* __restrict__ batch,
                                                   float* __restrict__ pooled, int N) {
    __shared__ int bounds[2];
    int g = blockIdx.x;
    if (threadIdx.x < 2) {
        int v = g + (int)threadIdx.x;   // lower_bound(batch, v)
        int lo = 0, hi = N;
        while (lo < hi) {
            int mid = (lo + hi) >> 1;
            if (batch[mid] < v) lo = mid + 1; else hi = mid;
        }
        bounds[threadIdx.x] = lo;
    }
    __syncthreads();
    int start = bounds[0], end = bounds[1];
    float s = 0.f;
    for (int n = start; n < end; ++n) s += Hin[(size_t)n * H_DIM + threadIdx.x];
    int cnt = end - start;
    pooled[g * H_DIM + threadIdx.x] = s / (float)(cnt > 0 ? cnt : 1);
}

// ---------------------------------------------------------------------------
// logits = pooled @ Wfc + bfc ; out = log_softmax(logits)
__global__ __launch_bounds__(64) void head_kernel(const float* __restrict__ pooled,
                                                  const float* __restrict__ Wfc,
                                                  const float* __restrict__ bfc,
                                                  float* __restrict__ out) {
    __shared__ float sl[OUT_DIM + 2];
    int g = blockIdx.x;
    int j = threadIdx.x;
    if (j < OUT_DIM) {
        float acc = bfc[j];
        const float* p = pooled + g * H_DIM;
        for (int k = 0; k < H_DIM; ++k) acc += p[k] * Wfc[k * OUT_DIM + j];
        sl[j] = acc;
    }
    __syncthreads();
    if (j == 0) {
        float m = sl[0];
        for (int i = 1; i < OUT_DIM; ++i) m = fmaxf(m, sl[i]);
        float s = 0.f;
        for (int i = 0; i < OUT_DIM; ++i) s += expf(sl[i] - m);
        sl[OUT_DIM] = m + logf(s);
    }
    __syncthreads();
    if (j < OUT_DIM) out[g * OUT_DIM + j] = sl[j] - sl[OUT_DIM];
}

// ---------------------------------------------------------------------------
extern "C" void kernel_launch(void* const* d_in, const int* in_sizes, int n_in,
                              void* d_out, int out_size, void* d_ws, size_t ws_size,
                              hipStream_t stream) {
    const float* x     = (const float*)d_in[0];
    const int*   ei    = (const int*)  d_in[1];
    const int*   batch = (const int*)  d_in[2];
    const float* W1    = (const float*)d_in[3];
    const float* b1    = (const float*)d_in[4];
    const float* W2    = (const float*)d_in[5];
    const float* b2    = (const float*)d_in[6];
    const float* Wfc   = (const float*)d_in[7];
    const float* bfc   = (const float*)d_in[8];
    float* out = (float*)d_out;

    int N = in_sizes[2];
    int E = in_sizes[1] / 2;
    int G = out_size / OUT_DIM;
    const int* row = ei;
    const int* col = ei + E;

    // Workspace layout (fp32): dinv[N] | bufA[N*128] | bufB[N*128] | pooled[G*128]
    float* ws   = (float*)d_ws;
    size_t nAlign = (size_t)((N + 255) / 256) * 256;
    size_t nh = (size_t)N * H_DIM;
    float* dinv   = ws;
    float* bufA   = ws + nAlign;
    float* bufB   = bufA + nh;
    float* pooled = bufB + nh;

    // Degrees -> dinv
    hipMemsetAsync(dinv, 0, N * sizeof(float), stream);
    deg_kernel<<<(E + 255) / 256, 256, 0, stream>>>(col, dinv, E);
    dinv_kernel<<<(N + 255) / 256, 256, 0, stream>>>(dinv, N);

    // ---- Layer 1: bufA = x@W1 ; bufB = scatter ; bufB = relu(bufB + self + b1)
    gemm_x_w<<<(N + 15) / 16, 256, 0, stream>>>(x, W1, bufA, N);
    hipMemsetAsync(bufB, 0, nh * sizeof(float), stream);
    agg_edges<<<(E + 3) / 4, 256, 0, stream>>>(bufA, dinv, row, col, bufB, E);
    self_bias_relu<<<((size_t)N * 32 + 255) / 256, 256, 0, stream>>>(bufA, dinv, b1, bufB, N);

    // ---- Layer 2: bufA = bufB@W2 ; bufB = scatter ; bufB = relu(bufB + self + b2)
    gemm_x_w<<<(N + 15) / 16, 256, 0, stream>>>(bufB, W2, bufA, N);
    hipMemsetAsync(bufB, 0, nh * sizeof(float), stream);
    agg_edges<<<(E + 3) / 4, 256, 0, stream>>>(bufA, dinv, row, col, bufB, E);
    self_bias_relu<<<((size_t)N * 32 + 255) / 256, 256, 0, stream>>>(bufA, dinv, b2, bufB, N);

    // ---- Pool + head
    pool_kernel<<<G, 128, 0, stream>>>(bufB, batch, pooled, N);
    head_kernel<<<G, 64, 0, stream>>>(pooled, Wfc, bfc, out);
}

// Round 2
// 554.509 us; speedup vs baseline: 2.4796x; 2.4796x over previous
//
#include <hip/hip_runtime.h>
#include <math.h>

#define H_DIM 128
#define OUT_DIM 10

// ---------------------------------------------------------------------------
// cnt[col[e]] += 1   (int histogram; self-loop +1 folded into dinv_kernel)
__global__ __launch_bounds__(256) void hist_kernel(const int* __restrict__ col,
                                                   int* __restrict__ cnt, int E) {
    int e = blockIdx.x * 256 + threadIdx.x;
    if (e < E) atomicAdd(&cnt[col[e]], 1);
}

__global__ __launch_bounds__(256) void dinv_kernel(const int* __restrict__ cnt,
                                                   float* __restrict__ dinv, int N) {
    int n = blockIdx.x * 256 + threadIdx.x;
    if (n < N) dinv[n] = rsqrtf((float)cnt[n] + 1.0f);   // deg>=1 (self loop)
}

// ---------------------------------------------------------------------------
// Single-block exclusive scan of cnt[N] -> offs[N+1]; also fills cursor = offs.
__global__ __launch_bounds__(1024) void scan_kernel(const int* __restrict__ cnt,
                                                    int* __restrict__ offs,
                                                    int* __restrict__ cursor, int N) {
    __shared__ int partial[1024];
    int t = threadIdx.x;
    int per = (N + 1023) / 1024;
    int s0 = t * per;
    int s1 = s0 + per; if (s1 > N) s1 = N; if (s0 > N) s0 = N;
    int sum = 0;
    for (int i = s0; i < s1; ++i) sum += cnt[i];
    partial[t] = sum;
    __syncthreads();
    for (int d = 1; d < 1024; d <<= 1) {
        int v = (t >= d) ? partial[t - d] : 0;
        __syncthreads();
        partial[t] += v;
        __syncthreads();
    }
    int run = (t == 0) ? 0 : partial[t - 1];
    for (int i = s0; i < s1; ++i) {
        offs[i] = run; cursor[i] = run; run += cnt[i];
    }
    if (t == 1023) offs[N] = run;   // == E
}

// ---------------------------------------------------------------------------
// csr[pos] = (row, norm) bucketed by col.
__global__ __launch_bounds__(256) void scatter_kernel(const int* __restrict__ row,
                                                      const int* __restrict__ col,
                                                      const float* __restrict__ dinv,
                                                      int* __restrict__ cursor,
                                                      int2* __restrict__ csr, int E) {
    int e = blockIdx.x * 256 + threadIdx.x;
    if (e >= E) return;
    int r = row[e], c = col[e];
    int pos = atomicAdd(&cursor[c], 1);
    int2 p; p.x = r; p.y = __float_as_int(dinv[r] * dinv[c]);
    csr[pos] = p;
}

// ---------------------------------------------------------------------------
// Y[N,128] = X[N,128] @ W[128,128].  W staged in LDS (64 KB).
__global__ __launch_bounds__(256) void gemm_x_w(const float* __restrict__ X,
                                                const float* __restrict__ W,
                                                float* __restrict__ Y, int N) {
    __shared__ float sW[H_DIM * H_DIM];
    float4* sW4 = (float4*)sW;
    const float4* W4 = (const float4*)W;
    for (int i = threadIdx.x; i < H_DIM * H_DIM / 4; i += 256) sW4[i] = W4[i];
    __syncthreads();

    int c  = threadIdx.x & 31;   // float4 column chunk
    int ng = threadIdx.x >> 5;   // 0..7
    int n0 = blockIdx.x * 16 + ng;
    int n1 = n0 + 8;
    bool v0 = n0 < N, v1 = n1 < N;
    const float* x0 = X + (size_t)n0 * H_DIM;
    const float* x1 = X + (size_t)n1 * H_DIM;

    float4 acc0 = {0.f, 0.f, 0.f, 0.f};
    float4 acc1 = {0.f, 0.f, 0.f, 0.f};
    for (int k = 0; k < H_DIM; ++k) {
        float4 w = sW4[k * 32 + c];
        float a0 = v0 ? x0[k] : 0.0f;
        float a1 = v1 ? x1[k] : 0.0f;
        acc0.x += a0 * w.x; acc0.y += a0 * w.y; acc0.z += a0 * w.z; acc0.w += a0 * w.w;
        acc1.x += a1 * w.x; acc1.y += a1 * w.y; acc1.z += a1 * w.z; acc1.w += a1 * w.w;
    }
    if (v0) ((float4*)(Y + (size_t)n0 * H_DIM))[c] = acc0;
    if (v1) ((float4*)(Y + (size_t)n1 * H_DIM))[c] = acc1;
}

// ---------------------------------------------------------------------------
// One wave per destination node: OUT[c,:] = relu( sum_in XW[r,:]*nrm
//                                                + XW[c,:]*dinv[c]^2 + bias )
__global__ __launch_bounds__(256) void agg_fused(const float* __restrict__ XW,
                                                 const float* __restrict__ dinv,
                                                 const int2* __restrict__ csr,
                                                 const int* __restrict__ offs,
                                                 const float* __restrict__ bias,
                                                 float* __restrict__ OUT, int N) {
    int wave = (blockIdx.x * 256 + threadIdx.x) >> 6;
    int lane = threadIdx.x & 63;
    if (wave >= N) return;
    int c = wave;
    int start = offs[c], end = offs[c + 1];
    float dc = dinv[c];

    float2 acc;
    {   // self loop
        float2 v = ((const float2*)(XW + (size_t)c * H_DIM))[lane];
        float s = dc * dc;
        acc.x = v.x * s; acc.y = v.y * s;
    }
    for (int i = start; i < end; ++i) {
        int2 p = csr[i];                        // broadcast load
        float nrm = __int_as_float(p.y);
        float2 u = ((const float2*)(XW + (size_t)p.x * H_DIM))[lane];
        acc.x += u.x * nrm; acc.y += u.y * nrm;
    }
    float2 b = ((const float2*)bias)[lane];
    acc.x = fmaxf(acc.x + b.x, 0.f);
    acc.y = fmaxf(acc.y + b.y, 0.f);
    ((float2*)(OUT + (size_t)c * H_DIM))[lane] = acc;
}

// ---------------------------------------------------------------------------
// Mean pool per graph (batch sorted -> binary-search bounds).
__global__ __launch_bounds__(128) void pool_kernel(const float* __restrict__ Hin,
                                                   const int* __restrict__ batch,
                                                   float* __restrict__ pooled, int N) {
    __shared__ int bounds[2];
    int g = blockIdx.x;
    if (threadIdx.x < 2) {
        int v = g + (int)threadIdx.x;
        int lo = 0, hi = N;
        while (lo < hi) {
            int mid = (lo + hi) >> 1;
            if (batch[mid] < v) lo = mid + 1; else hi = mid;
        }
        bounds[threadIdx.x] = lo;
    }
    __syncthreads();
    int start = bounds[0], end = bounds[1];
    float s = 0.f;
    for (int n = start; n < end; ++n) s += Hin[(size_t)n * H_DIM + threadIdx.x];
    int cnt = end - start;
    pooled[g * H_DIM + threadIdx.x] = s / (float)(cnt > 0 ? cnt : 1);
}

// ---------------------------------------------------------------------------
__global__ __launch_bounds__(64) void head_kernel(const float* __restrict__ pooled,
                                                  const float* __restrict__ Wfc,
                                                  const float* __restrict__ bfc,
                                                  float* __restrict__ out) {
    __shared__ float sl[OUT_DIM + 2];
    int g = blockIdx.x;
    int j = threadIdx.x;
    if (j < OUT_DIM) {
        float acc = bfc[j];
        const float* p = pooled + g * H_DIM;
        for (int k = 0; k < H_DIM; ++k) acc += p[k] * Wfc[k * OUT_DIM + j];
        sl[j] = acc;
    }
    __syncthreads();
    if (j == 0) {
        float m = sl[0];
        for (int i = 1; i < OUT_DIM; ++i) m = fmaxf(m, sl[i]);
        float s = 0.f;
        for (int i = 0; i < OUT_DIM; ++i) s += expf(sl[i] - m);
        sl[OUT_DIM] = m + logf(s);
    }
    __syncthreads();
    if (j < OUT_DIM) out[g * OUT_DIM + j] = sl[j] - sl[OUT_DIM];
}

// ---------------------------------------------------------------------------
extern "C" void kernel_launch(void* const* d_in, const int* in_sizes, int n_in,
                              void* d_out, int out_size, void* d_ws, size_t ws_size,
                              hipStream_t stream) {
    const float* x     = (const float*)d_in[0];
    const int*   ei    = (const int*)  d_in[1];
    const int*   batch = (const int*)  d_in[2];
    const float* W1    = (const float*)d_in[3];
    const float* b1    = (const float*)d_in[4];
    const float* W2    = (const float*)d_in[5];
    const float* b2    = (const float*)d_in[6];
    const float* Wfc   = (const float*)d_in[7];
    const float* bfc   = (const float*)d_in[8];
    float* out = (float*)d_out;

    int N = in_sizes[2];
    int E = in_sizes[1] / 2;
    int G = out_size / OUT_DIM;
    const int* row = ei;
    const int* col = ei + E;

    // Workspace layout (all 4-byte elems):
    // cnt[N] | offs[N+1] | cursor[N] | dinv[N] | csr[2E] | bufA[N*128] | bufB[N*128] | pooled[G*128]
    char* wsb = (char*)d_ws;
    size_t nAlign = (size_t)((N + 256) / 256) * 256;   // >= N+1, 1KB-aligned elems
    int*   cnt    = (int*)wsb;
    int*   offs   = cnt + nAlign;
    int*   cursor = offs + nAlign;
    float* dinv   = (float*)(cursor + nAlign);
    int2*  csr    = (int2*)(dinv + nAlign);            // int2 is 8B-aligned: nAlign*4 %8==0
    float* bufA   = (float*)(csr + E);
    float* bufB   = bufA + (size_t)N * H_DIM;
    float* pooled = bufB + (size_t)N * H_DIM;

    // ---- Build dinv + CSR (by destination col)
    hipMemsetAsync(cnt, 0, N * sizeof(int), stream);
    hist_kernel<<<(E + 255) / 256, 256, 0, stream>>>(col, cnt, E);
    dinv_kernel<<<(N + 255) / 256, 256, 0, stream>>>(cnt, dinv, N);
    scan_kernel<<<1, 1024, 0, stream>>>(cnt, offs, cursor, N);
    scatter_kernel<<<(E + 255) / 256, 256, 0, stream>>>(row, col, dinv, cursor, csr, E);

    int aggBlocks = (N + 3) / 4;   // 4 waves/block, 1 wave/node

    // ---- Layer 1
    gemm_x_w<<<(N + 15) / 16, 256, 0, stream>>>(x, W1, bufA, N);
    agg_fused<<<aggBlocks, 256, 0, stream>>>(bufA, dinv, csr, offs, b1, bufB, N);

    // ---- Layer 2
    gemm_x_w<<<(N + 15) / 16, 256, 0, stream>>>(bufB, W2, bufA, N);
    agg_fused<<<aggBlocks, 256, 0, stream>>>(bufA, dinv, csr, offs, b2, bufB, N);

    // ---- Pool + head
    pool_kernel<<<G, 128, 0, stream>>>(bufB, batch, pooled, N);
    head_kernel<<<G, 64, 0, stream>>>(pooled, Wfc, bfc, out);
}

// Round 3
// 475.718 us; speedup vs baseline: 2.8903x; 1.1656x over previous
//
#include <hip/hip_runtime.h>
#include <math.h>

#define H_DIM 128
#define OUT_DIM 10

// ---------------------------------------------------------------------------
// cnt[col[e]] += 1   (int histogram; self-loop +1 folded into dinv_kernel)
__global__ __launch_bounds__(256) void hist_kernel(const int* __restrict__ col,
                                                   int* __restrict__ cnt, int E) {
    int e = blockIdx.x * 256 + threadIdx.x;
    if (e < E) atomicAdd(&cnt[col[e]], 1);
}

__global__ __launch_bounds__(256) void dinv_kernel(const int* __restrict__ cnt,
                                                   float* __restrict__ dinv, int N) {
    int n = blockIdx.x * 256 + threadIdx.x;
    if (n < N) dinv[n] = rsqrtf((float)cnt[n] + 1.0f);   // deg>=1 (self loop)
}

// ---------------------------------------------------------------------------
// Hierarchical scan: phase1 block-reduce, phase2 scan partials, phase3 local
// scan + offset.  1024 elements per block.
__global__ __launch_bounds__(256) void scan_phase1(const int* __restrict__ cnt,
                                                   int* __restrict__ blockSums, int N) {
    __shared__ int red[256];
    int base = blockIdx.x * 1024;
    int t = threadIdx.x;
    int s = 0;
    for (int i = 0; i < 4; ++i) {
        int idx = base + t * 4 + i;
        if (idx < N) s += cnt[idx];
    }
    red[t] = s;
    __syncthreads();
    for (int d = 128; d > 0; d >>= 1) {
        if (t < d) red[t] += red[t + d];
        __syncthreads();
    }
    if (t == 0) blockSums[blockIdx.x] = red[0];
}

// Single block; B <= 256 block partials.
__global__ __launch_bounds__(256) void scan_phase2(const int* __restrict__ blockSums,
                                                   int* __restrict__ blockOffs,
                                                   int* __restrict__ offs, int B, int N) {
    __shared__ int sh[256];
    int t = threadIdx.x;
    sh[t] = (t < B) ? blockSums[t] : 0;
    __syncthreads();
    for (int d = 1; d < 256; d <<= 1) {
        int v = (t >= d) ? sh[t - d] : 0;
        __syncthreads();
        sh[t] += v;
        __syncthreads();
    }
    if (t < B) blockOffs[t] = (t == 0) ? 0 : sh[t - 1];
    if (t == 255) offs[N] = sh[255];   // == E
}

__global__ __launch_bounds__(256) void scan_phase3(const int* __restrict__ cnt,
                                                   const int* __restrict__ blockOffs,
                                                   int* __restrict__ offs,
                                                   int* __restrict__ cursor, int N) {
    __shared__ int red[256];
    int base = blockIdx.x * 1024;
    int t = threadIdx.x;
    int v[4];
    int s = 0;
    for (int i = 0; i < 4; ++i) {
        int idx = base + t * 4 + i;
        v[i] = (idx < N) ? cnt[idx] : 0;
        s += v[i];
    }
    red[t] = s;
    __syncthreads();
    for (int d = 1; d < 256; d <<= 1) {   // inclusive Hillis-Steele
        int x = (t >= d) ? red[t - d] : 0;
        __syncthreads();
        red[t] += x;
        __syncthreads();
    }
    int run = blockOffs[blockIdx.x] + ((t == 0) ? 0 : red[t - 1]);
    for (int i = 0; i < 4; ++i) {
        int idx = base + t * 4 + i;
        if (idx < N) { offs[idx] = run; cursor[idx] = run; run += v[i]; }
    }
}

// ---------------------------------------------------------------------------
// csr[pos] = (row, norm) bucketed by col.
__global__ __launch_bounds__(256) void scatter_kernel(const int* __restrict__ row,
                                                      const int* __restrict__ col,
                                                      const float* __restrict__ dinv,
                                                      int* __restrict__ cursor,
                                                      int2* __restrict__ csr, int E) {
    int e = blockIdx.x * 256 + threadIdx.x;
    if (e >= E) return;
    int r = row[e], c = col[e];
    int pos = atomicAdd(&cursor[c], 1);
    int2 p; p.x = r; p.y = __float_as_int(dinv[r] * dinv[c]);
    csr[pos] = p;
}

// ---------------------------------------------------------------------------
// Y[N,128] = X[N,128] @ W[128,128].  W staged in LDS (64 KB).
__global__ __launch_bounds__(256) void gemm_x_w(const float* __restrict__ X,
                                                const float* __restrict__ W,
                                                float* __restrict__ Y, int N) {
    __shared__ float sW[H_DIM * H_DIM];
    float4* sW4 = (float4*)sW;
    const float4* W4 = (const float4*)W;
    for (int i = threadIdx.x; i < H_DIM * H_DIM / 4; i += 256) sW4[i] = W4[i];
    __syncthreads();

    int c  = threadIdx.x & 31;   // float4 column chunk
    int ng = threadIdx.x >> 5;   // 0..7
    int n0 = blockIdx.x * 16 + ng;
    int n1 = n0 + 8;
    bool v0 = n0 < N, v1 = n1 < N;
    const float* x0 = X + (size_t)n0 * H_DIM;
    const float* x1 = X + (size_t)n1 * H_DIM;

    float4 acc0 = {0.f, 0.f, 0.f, 0.f};
    float4 acc1 = {0.f, 0.f, 0.f, 0.f};
    for (int k = 0; k < H_DIM; ++k) {
        float4 w = sW4[k * 32 + c];
        float a0 = v0 ? x0[k] : 0.0f;
        float a1 = v1 ? x1[k] : 0.0f;
        acc0.x += a0 * w.x; acc0.y += a0 * w.y; acc0.z += a0 * w.z; acc0.w += a0 * w.w;
        acc1.x += a1 * w.x; acc1.y += a1 * w.y; acc1.z += a1 * w.z; acc1.w += a1 * w.w;
    }
    if (v0) ((float4*)(Y + (size_t)n0 * H_DIM))[c] = acc0;
    if (v1) ((float4*)(Y + (size_t)n1 * H_DIM))[c] = acc1;
}

// ---------------------------------------------------------------------------
// One wave per destination node: OUT[c,:] = relu( sum_in XW[r,:]*nrm
//                                                + XW[c,:]*dinv[c]^2 + bias )
__global__ __launch_bounds__(256) void agg_fused(const float* __restrict__ XW,
                                                 const float* __restrict__ dinv,
                                                 const int2* __restrict__ csr,
                                                 const int* __restrict__ offs,
                                                 const float* __restrict__ bias,
                                                 float* __restrict__ OUT, int N) {
    int wave = (blockIdx.x * 256 + threadIdx.x) >> 6;
    int lane = threadIdx.x & 63;
    if (wave >= N) return;
    int c = wave;
    int start = offs[c], end = offs[c + 1];
    float dc = dinv[c];

    float2 acc;
    {   // self loop
        float2 v = ((const float2*)(XW + (size_t)c * H_DIM))[lane];
        float s = dc * dc;
        acc.x = v.x * s; acc.y = v.y * s;
    }
    for (int i = start; i < end; ++i) {
        int2 p = csr[i];                        // broadcast load
        float nrm = __int_as_float(p.y);
        float2 u = ((const float2*)(XW + (size_t)p.x * H_DIM))[lane];
        acc.x += u.x * nrm; acc.y += u.y * nrm;
    }
    float2 b = ((const float2*)bias)[lane];
    acc.x = fmaxf(acc.x + b.x, 0.f);
    acc.y = fmaxf(acc.y + b.y, 0.f);
    ((float2*)(OUT + (size_t)c * H_DIM))[lane] = acc;
}

// ---------------------------------------------------------------------------
// Mean pool per graph (batch sorted -> binary-search bounds).
__global__ __launch_bounds__(128) void pool_kernel(const float* __restrict__ Hin,
                                                   const int* __restrict__ batch,
                                                   float* __restrict__ pooled, int N) {
    __shared__ int bounds[2];
    int g = blockIdx.x;
    if (threadIdx.x < 2) {
        int v = g + (int)threadIdx.x;
        int lo = 0, hi = N;
        while (lo < hi) {
            int mid = (lo + hi) >> 1;
            if (batch[mid] < v) lo = mid + 1; else hi = mid;
        }
        bounds[threadIdx.x] = lo;
    }
    __syncthreads();
    int start = bounds[0], end = bounds[1];
    float s = 0.f;
    for (int n = start; n < end; ++n) s += Hin[(size_t)n * H_DIM + threadIdx.x];
    int cnt = end - start;
    pooled[g * H_DIM + threadIdx.x] = s / (float)(cnt > 0 ? cnt : 1);
}

// ---------------------------------------------------------------------------
__global__ __launch_bounds__(64) void head_kernel(const float* __restrict__ pooled,
                                                  const float* __restrict__ Wfc,
                                                  const float* __restrict__ bfc,
                                                  float* __restrict__ out) {
    __shared__ float sl[OUT_DIM + 2];
    int g = blockIdx.x;
    int j = threadIdx.x;
    if (j < OUT_DIM) {
        float acc = bfc[j];
        const float* p = pooled + g * H_DIM;
        for (int k = 0; k < H_DIM; ++k) acc += p[k] * Wfc[k * OUT_DIM + j];
        sl[j] = acc;
    }
    __syncthreads();
    if (j == 0) {
        float m = sl[0];
        for (int i = 1; i < OUT_DIM; ++i) m = fmaxf(m, sl[i]);
        float s = 0.f;
        for (int i = 0; i < OUT_DIM; ++i) s += expf(sl[i] - m);
        sl[OUT_DIM] = m + logf(s);
    }
    __syncthreads();
    if (j < OUT_DIM) out[g * OUT_DIM + j] = sl[j] - sl[OUT_DIM];
}

// ---------------------------------------------------------------------------
extern "C" void kernel_launch(void* const* d_in, const int* in_sizes, int n_in,
                              void* d_out, int out_size, void* d_ws, size_t ws_size,
                              hipStream_t stream) {
    const float* x     = (const float*)d_in[0];
    const int*   ei    = (const int*)  d_in[1];
    const int*   batch = (const int*)  d_in[2];
    const float* W1    = (const float*)d_in[3];
    const float* b1    = (const float*)d_in[4];
    const float* W2    = (const float*)d_in[5];
    const float* b2    = (const float*)d_in[6];
    const float* Wfc   = (const float*)d_in[7];
    const float* bfc   = (const float*)d_in[8];
    float* out = (float*)d_out;

    int N = in_sizes[2];
    int E = in_sizes[1] / 2;
    int G = out_size / OUT_DIM;
    const int* row = ei;
    const int* col = ei + E;

    // Workspace layout (all 4-byte elems):
    // cnt[N] | offs[N+1] | cursor[N] | dinv[N] | csr[2E] | bufA[N*128] | bufB[N*128]
    //   | pooled[G*128] | blockSums[256] | blockOffs[256]
    char* wsb = (char*)d_ws;
    size_t nAlign = (size_t)((N + 256) / 256) * 256;   // >= N+1
    int*   cnt    = (int*)wsb;
    int*   offs   = cnt + nAlign;
    int*   cursor = offs + nAlign;
    float* dinv   = (float*)(cursor + nAlign);
    int2*  csr    = (int2*)(dinv + nAlign);
    float* bufA   = (float*)(csr + E);
    float* bufB   = bufA + (size_t)N * H_DIM;
    float* pooled = bufB + (size_t)N * H_DIM;
    int* blockSums = (int*)(pooled + (size_t)G * H_DIM);
    int* blockOffs = blockSums + 256;

    int scanBlocks = (N + 1023) / 1024;   // 40 for N=40000 (<=256 supported)

    // ---- Build dinv + CSR (by destination col)
    hipMemsetAsync(cnt, 0, N * sizeof(int), stream);
    hist_kernel<<<(E + 255) / 256, 256, 0, stream>>>(col, cnt, E);
    dinv_kernel<<<(N + 255) / 256, 256, 0, stream>>>(cnt, dinv, N);
    scan_phase1<<<scanBlocks, 256, 0, stream>>>(cnt, blockSums, N);
    scan_phase2<<<1, 256, 0, stream>>>(blockSums, blockOffs, offs, scanBlocks, N);
    scan_phase3<<<scanBlocks, 256, 0, stream>>>(cnt, blockOffs, offs, cursor, N);
    scatter_kernel<<<(E + 255) / 256, 256, 0, stream>>>(row, col, dinv, cursor, csr, E);

    int aggBlocks = (N + 3) / 4;   // 4 waves/block, 1 wave/node

    // ---- Layer 1
    gemm_x_w<<<(N + 15) / 16, 256, 0, stream>>>(x, W1, bufA, N);
    agg_fused<<<aggBlocks, 256, 0, stream>>>(bufA, dinv, csr, offs, b1, bufB, N);

    // ---- Layer 2
    gemm_x_w<<<(N + 15) / 16, 256, 0, stream>>>(bufB, W2, bufA, N);
    agg_fused<<<aggBlocks, 256, 0, stream>>>(bufA, dinv, csr, offs, b2, bufB, N);

    // ---- Pool + head
    pool_kernel<<<G, 128, 0, stream>>>(bufB, batch, pooled, N);
    head_kernel<<<G, 64, 0, stream>>>(pooled, Wfc, bfc, out);
}

// Round 4
// 387.475 us; speedup vs baseline: 3.5485x; 1.2277x over previous
//
#include <hip/hip_runtime.h>
#include <math.h>

#define H_DIM 128
#define OUT_DIM 10

typedef __attribute__((ext_vector_type(8))) __bf16 bf16x8;
typedef __attribute__((ext_vector_type(8))) unsigned short ushort8;
typedef __attribute__((ext_vector_type(4))) float f32x4;

__device__ inline unsigned short f2bf_rne(float f) {
    unsigned int u = __float_as_uint(f);
    unsigned int r = u + 0x7FFFu + ((u >> 16) & 1u);
    return (unsigned short)(r >> 16);
}

// ---------------------------------------------------------------------------
// cnt[col[e]] += 1   (int histogram; self-loop +1 folded into dinv_kernel)
__global__ __launch_bounds__(256) void hist_kernel(const int* __restrict__ col,
                                                   int* __restrict__ cnt, int E) {
    int e = blockIdx.x * 256 + threadIdx.x;
    if (e < E) atomicAdd(&cnt[col[e]], 1);
}

__global__ __launch_bounds__(256) void dinv_kernel(const int* __restrict__ cnt,
                                                   float* __restrict__ dinv, int N) {
    int n = blockIdx.x * 256 + threadIdx.x;
    if (n < N) dinv[n] = rsqrtf((float)cnt[n] + 1.0f);   // deg>=1 (self loop)
}

// ---------------------------------------------------------------------------
// Hierarchical scan.
__global__ __launch_bounds__(256) void scan_phase1(const int* __restrict__ cnt,
                                                   int* __restrict__ blockSums, int N) {
    __shared__ int red[256];
    int base = blockIdx.x * 1024;
    int t = threadIdx.x;
    int s = 0;
    for (int i = 0; i < 4; ++i) {
        int idx = base + t * 4 + i;
        if (idx < N) s += cnt[idx];
    }
    red[t] = s;
    __syncthreads();
    for (int d = 128; d > 0; d >>= 1) {
        if (t < d) red[t] += red[t + d];
        __syncthreads();
    }
    if (t == 0) blockSums[blockIdx.x] = red[0];
}

__global__ __launch_bounds__(256) void scan_phase2(const int* __restrict__ blockSums,
                                                   int* __restrict__ blockOffs,
                                                   int* __restrict__ offs, int B, int N) {
    __shared__ int sh[256];
    int t = threadIdx.x;
    sh[t] = (t < B) ? blockSums[t] : 0;
    __syncthreads();
    for (int d = 1; d < 256; d <<= 1) {
        int v = (t >= d) ? sh[t - d] : 0;
        __syncthreads();
        sh[t] += v;
        __syncthreads();
    }
    if (t < B) blockOffs[t] = (t == 0) ? 0 : sh[t - 1];
    if (t == 255) offs[N] = sh[255];   // == E
}

__global__ __launch_bounds__(256) void scan_phase3(const int* __restrict__ cnt,
                                                   const int* __restrict__ blockOffs,
                                                   int* __restrict__ offs,
                                                   int* __restrict__ cursor, int N) {
    __shared__ int red[256];
    int base = blockIdx.x * 1024;
    int t = threadIdx.x;
    int v[4];
    int s = 0;
    for (int i = 0; i < 4; ++i) {
        int idx = base + t * 4 + i;
        v[i] = (idx < N) ? cnt[idx] : 0;
        s += v[i];
    }
    red[t] = s;
    __syncthreads();
    for (int d = 1; d < 256; d <<= 1) {   // inclusive Hillis-Steele
        int x = (t >= d) ? red[t - d] : 0;
        __syncthreads();
        red[t] += x;
        __syncthreads();
    }
    int run = blockOffs[blockIdx.x] + ((t == 0) ? 0 : red[t - 1]);
    for (int i = 0; i < 4; ++i) {
        int idx = base + t * 4 + i;
        if (idx < N) { offs[idx] = run; cursor[idx] = run; run += v[i]; }
    }
}

// ---------------------------------------------------------------------------
// csr[pos] = (row, norm) bucketed by col.
__global__ __launch_bounds__(256) void scatter_kernel(const int* __restrict__ row,
                                                      const int* __restrict__ col,
                                                      const float* __restrict__ dinv,
                                                      int* __restrict__ cursor,
                                                      int2* __restrict__ csr, int E) {
    int e = blockIdx.x * 256 + threadIdx.x;
    if (e >= E) return;
    int r = row[e], c = col[e];
    int pos = atomicAdd(&cursor[c], 1);
    int2 p; p.x = r; p.y = __float_as_int(dinv[r] * dinv[c]);
    csr[pos] = p;
}

// ---------------------------------------------------------------------------
// Split W (fp32 [k][n]) into transposed bf16 hi/lo planes [n][k] for MFMA
// B-fragments (contiguous 8 along k).  Both layers in one launch (i < 32768).
__global__ __launch_bounds__(256) void wconvert(const float* __restrict__ W1,
                                                const float* __restrict__ W2,
                                                unsigned short* __restrict__ Wt1Hi,
                                                unsigned short* __restrict__ Wt1Lo,
                                                unsigned short* __restrict__ Wt2Hi,
                                                unsigned short* __restrict__ Wt2Lo) {
    int i = blockIdx.x * 256 + threadIdx.x;   // 0..32767
    const float* src       = (i < 16384) ? W1    : W2;
    unsigned short* dh     = (i < 16384) ? Wt1Hi : Wt2Hi;
    unsigned short* dl     = (i < 16384) ? Wt1Lo : Wt2Lo;
    int idx = i & 16383;
    int k = idx >> 7, n = idx & 127;
    float v = src[idx];                        // W[k][n]
    unsigned short hb = f2bf_rne(v);
    float hf = __uint_as_float((unsigned int)hb << 16);
    unsigned short lb = f2bf_rne(v - hf);
    dh[n * H_DIM + k] = hb;
    dl[n * H_DIM + k] = lb;
}

// ---------------------------------------------------------------------------
// Y[N,128] = X[N,128] @ W[128,128] via split-bf16 MFMA (hi*Hi + lo*Hi + hi*Lo).
// Block: 256 thr = 4 waves; 32 nodes x 128 cols per block.  Wave w covers
// col-tiles {2w, 2w+1}; node-tiles {0,1}.  Verified gfx950 layouts:
//   A[m=lane&15][k=quad*8+j]  B[k=quad*8+j][n=lane&15]  D[row=quad*4+r][col=lane&15]
__global__ __launch_bounds__(256) void gemm_mfma(const float* __restrict__ X,
                                                 const unsigned short* __restrict__ WtHi,
                                                 const unsigned short* __restrict__ WtLo,
                                                 float* __restrict__ Y, int N) {
    int lane = threadIdx.x & 63;
    int wv   = threadIdx.x >> 6;    // 0..3
    int m16  = lane & 15;
    int quad = lane >> 4;
    int nodeBase = blockIdx.x * 32;

    f32x4 acc[2][2] = {};

    #pragma unroll
    for (int kt = 0; kt < 4; ++kt) {
        int k0 = kt * 32 + quad * 8;

        ushort8 aHi[2], aLo[2];
        #pragma unroll
        for (int mi = 0; mi < 2; ++mi) {
            int node = nodeBase + mi * 16 + m16;
            if (node >= N) node = N - 1;           // clamp: row-local garbage, store-guarded
            const float* xp = X + (size_t)node * H_DIM + k0;
            float xv[8];
            *(f32x4*)&xv[0] = *(const f32x4*)xp;
            *(f32x4*)&xv[4] = *(const f32x4*)(xp + 4);
            ushort8 h, l;
            #pragma unroll
            for (int j = 0; j < 8; ++j) {
                unsigned short hb = f2bf_rne(xv[j]);
                float hf = __uint_as_float((unsigned int)hb << 16);
                h[j] = hb;
                l[j] = f2bf_rne(xv[j] - hf);
            }
            aHi[mi] = h; aLo[mi] = l;
        }

        ushort8 bHi[2], bLo[2];
        #pragma unroll
        for (int ni = 0; ni < 2; ++ni) {
            int n = (wv * 2 + ni) * 16 + m16;
            size_t off = (size_t)n * H_DIM + k0;
            bHi[ni] = *(const ushort8*)(WtHi + off);
            bLo[ni] = *(const ushort8*)(WtLo + off);
        }

        #pragma unroll
        for (int mi = 0; mi < 2; ++mi)
            #pragma unroll
            for (int ni = 0; ni < 2; ++ni) {
                acc[mi][ni] = __builtin_amdgcn_mfma_f32_16x16x32_bf16(
                    __builtin_bit_cast(bf16x8, aHi[mi]),
                    __builtin_bit_cast(bf16x8, bHi[ni]), acc[mi][ni], 0, 0, 0);
                acc[mi][ni] = __builtin_amdgcn_mfma_f32_16x16x32_bf16(
                    __builtin_bit_cast(bf16x8, aLo[mi]),
                    __builtin_bit_cast(bf16x8, bHi[ni]), acc[mi][ni], 0, 0, 0);
                acc[mi][ni] = __builtin_amdgcn_mfma_f32_16x16x32_bf16(
                    __builtin_bit_cast(bf16x8, aHi[mi]),
                    __builtin_bit_cast(bf16x8, bLo[ni]), acc[mi][ni], 0, 0, 0);
            }
    }

    #pragma unroll
    for (int mi = 0; mi < 2; ++mi)
        #pragma unroll
        for (int r = 0; r < 4; ++r) {
            int node = nodeBase + mi * 16 + quad * 4 + r;
            if (node < N) {
                #pragma unroll
                for (int ni = 0; ni < 2; ++ni) {
                    int c = (wv * 2 + ni) * 16 + m16;
                    Y[(size_t)node * H_DIM + c] = acc[mi][ni][r];
                }
            }
        }
}

// ---------------------------------------------------------------------------
// One wave per destination node: OUT[c,:] = relu( sum_in XW[r,:]*nrm
//                                                + XW[c,:]*dinv[c]^2 + bias )
__global__ __launch_bounds__(256) void agg_fused(const float* __restrict__ XW,
                                                 const float* __restrict__ dinv,
                                                 const int2* __restrict__ csr,
                                                 const int* __restrict__ offs,
                                                 const float* __restrict__ bias,
                                                 float* __restrict__ OUT, int N) {
    int wave = (blockIdx.x * 256 + threadIdx.x) >> 6;
    int lane = threadIdx.x & 63;
    if (wave >= N) return;
    int c = wave;
    int start = offs[c], end = offs[c + 1];
    float dc = dinv[c];

    float2 acc;
    {   // self loop
        float2 v = ((const float2*)(XW + (size_t)c * H_DIM))[lane];
        float s = dc * dc;
        acc.x = v.x * s; acc.y = v.y * s;
    }
    for (int i = start; i < end; ++i) {
        int2 p = csr[i];                        // broadcast load
        float nrm = __int_as_float(p.y);
        float2 u = ((const float2*)(XW + (size_t)p.x * H_DIM))[lane];
        acc.x += u.x * nrm; acc.y += u.y * nrm;
    }
    float2 b = ((const float2*)bias)[lane];
    acc.x = fmaxf(acc.x + b.x, 0.f);
    acc.y = fmaxf(acc.y + b.y, 0.f);
    ((float2*)(OUT + (size_t)c * H_DIM))[lane] = acc;
}

// ---------------------------------------------------------------------------
// Mean pool per graph (batch sorted -> binary-search bounds).
__global__ __launch_bounds__(128) void pool_kernel(const float* __restrict__ Hin,
                                                   const int* __restrict__ batch,
                                                   float* __restrict__ pooled, int N) {
    __shared__ int bounds[2];
    int g = blockIdx.x;
    if (threadIdx.x < 2) {
        int v = g + (int)threadIdx.x;
        int lo = 0, hi = N;
        while (lo < hi) {
            int mid = (lo + hi) >> 1;
            if (batch[mid] < v) lo = mid + 1; else hi = mid;
        }
        bounds[threadIdx.x] = lo;
    }
    __syncthreads();
    int start = bounds[0], end = bounds[1];
    float s = 0.f;
    for (int n = start; n < end; ++n) s += Hin[(size_t)n * H_DIM + threadIdx.x];
    int cnt = end - start;
    pooled[g * H_DIM + threadIdx.x] = s / (float)(cnt > 0 ? cnt : 1);
}

// ---------------------------------------------------------------------------
__global__ __launch_bounds__(64) void head_kernel(const float* __restrict__ pooled,
                                                  const float* __restrict__ Wfc,
                                                  const float* __restrict__ bfc,
                                                  float* __restrict__ out) {
    __shared__ float sl[OUT_DIM + 2];
    int g = blockIdx.x;
    int j = threadIdx.x;
    if (j < OUT_DIM) {
        float acc = bfc[j];
        const float* p = pooled + g * H_DIM;
        for (int k = 0; k < H_DIM; ++k) acc += p[k] * Wfc[k * OUT_DIM + j];
        sl[j] = acc;
    }
    __syncthreads();
    if (j == 0) {
        float m = sl[0];
        for (int i = 1; i < OUT_DIM; ++i) m = fmaxf(m, sl[i]);
        float s = 0.f;
        for (int i = 0; i < OUT_DIM; ++i) s += expf(sl[i] - m);
        sl[OUT_DIM] = m + logf(s);
    }
    __syncthreads();
    if (j < OUT_DIM) out[g * OUT_DIM + j] = sl[j] - sl[OUT_DIM];
}

// ---------------------------------------------------------------------------
extern "C" void kernel_launch(void* const* d_in, const int* in_sizes, int n_in,
                              void* d_out, int out_size, void* d_ws, size_t ws_size,
                              hipStream_t stream) {
    const float* x     = (const float*)d_in[0];
    const int*   ei    = (const int*)  d_in[1];
    const int*   batch = (const int*)  d_in[2];
    const float* W1    = (const float*)d_in[3];
    const float* b1    = (const float*)d_in[4];
    const float* W2    = (const float*)d_in[5];
    const float* b2    = (const float*)d_in[6];
    const float* Wfc   = (const float*)d_in[7];
    const float* bfc   = (const float*)d_in[8];
    float* out = (float*)d_out;

    int N = in_sizes[2];
    int E = in_sizes[1] / 2;
    int G = out_size / OUT_DIM;
    const int* row = ei;
    const int* col = ei + E;

    // Workspace layout (4-byte elems unless noted):
    // cnt[N] | offs[N+1] | cursor[N] | dinv[N] | csr[2E] | bufA[N*128] | bufB[N*128]
    //   | pooled[G*128] | blockSums[256] | blockOffs[256] | Wt{1,2}{Hi,Lo}[128*128] ushort
    char* wsb = (char*)d_ws;
    size_t nAlign = (size_t)((N + 256) / 256) * 256;   // >= N+1
    int*   cnt    = (int*)wsb;
    int*   offs   = cnt + nAlign;
    int*   cursor = offs + nAlign;
    float* dinv   = (float*)(cursor + nAlign);
    int2*  csr    = (int2*)(dinv + nAlign);
    float* bufA   = (float*)(csr + E);
    float* bufB   = bufA + (size_t)N * H_DIM;
    float* pooled = bufB + (size_t)N * H_DIM;
    int* blockSums = (int*)(pooled + (size_t)G * H_DIM);
    int* blockOffs = blockSums + 256;
    unsigned short* Wt1Hi = (unsigned short*)(blockOffs + 256);
    unsigned short* Wt1Lo = Wt1Hi + H_DIM * H_DIM;
    unsigned short* Wt2Hi = Wt1Lo + H_DIM * H_DIM;
    unsigned short* Wt2Lo = Wt2Hi + H_DIM * H_DIM;

    int scanBlocks = (N + 1023) / 1024;   // 40 for N=40000 (<=256 supported)

    // ---- W split/transpose for MFMA
    wconvert<<<128, 256, 0, stream>>>(W1, W2, Wt1Hi, Wt1Lo, Wt2Hi, Wt2Lo);

    // ---- Build dinv + CSR (by destination col)
    hipMemsetAsync(cnt, 0, N * sizeof(int), stream);
    hist_kernel<<<(E + 255) / 256, 256, 0, stream>>>(col, cnt, E);
    dinv_kernel<<<(N + 255) / 256, 256, 0, stream>>>(cnt, dinv, N);
    scan_phase1<<<scanBlocks, 256, 0, stream>>>(cnt, blockSums, N);
    scan_phase2<<<1, 256, 0, stream>>>(blockSums, blockOffs, offs, scanBlocks, N);
    scan_phase3<<<scanBlocks, 256, 0, stream>>>(cnt, blockOffs, offs, cursor, N);
    scatter_kernel<<<(E + 255) / 256, 256, 0, stream>>>(row, col, dinv, cursor, csr, E);

    int aggBlocks  = (N + 3) / 4;     // 4 waves/block, 1 wave/node
    int gemmBlocks = (N + 31) / 32;   // 32 nodes/block

    // ---- Layer 1
    gemm_mfma<<<gemmBlocks, 256, 0, stream>>>(x, Wt1Hi, Wt1Lo, bufA, N);
    agg_fused<<<aggBlocks, 256, 0, stream>>>(bufA, dinv, csr, offs, b1, bufB, N);

    // ---- Layer 2
    gemm_mfma<<<gemmBlocks, 256, 0, stream>>>(bufB, Wt2Hi, Wt2Lo, bufA, N);
    agg_fused<<<aggBlocks, 256, 0, stream>>>(bufA, dinv, csr, offs, b2, bufB, N);

    // ---- Pool + head
    pool_kernel<<<G, 128, 0, stream>>>(bufB, batch, pooled, N);
    head_kernel<<<G, 64, 0, stream>>>(pooled, Wfc, bfc, out);
}

// Round 5
// 330.520 us; speedup vs baseline: 4.1600x; 1.1723x over previous
//
#include <hip/hip_runtime.h>
#include <math.h>

#define H_DIM 128
#define OUT_DIM 10

typedef __attribute__((ext_vector_type(8))) __bf16 bf16x8;
typedef __attribute__((ext_vector_type(8))) unsigned short ushort8;
typedef __attribute__((ext_vector_type(4))) float f32x4;

__device__ inline unsigned short f2bf_rne(float f) {
    unsigned int u = __float_as_uint(f);
    unsigned int r = u + 0x7FFFu + ((u >> 16) & 1u);
    return (unsigned short)(r >> 16);
}
__device__ inline float bf_lo(unsigned int u) { return __uint_as_float(u << 16); }
__device__ inline float bf_hi(unsigned int u) { return __uint_as_float(u & 0xFFFF0000u); }

// ---------------------------------------------------------------------------
__global__ __launch_bounds__(256) void hist_kernel(const int* __restrict__ col,
                                                   int* __restrict__ cnt, int E) {
    int e = blockIdx.x * 256 + threadIdx.x;
    if (e < E) atomicAdd(&cnt[col[e]], 1);
}

__global__ __launch_bounds__(256) void dinv_kernel(const int* __restrict__ cnt,
                                                   float* __restrict__ dinv, int N) {
    int n = blockIdx.x * 256 + threadIdx.x;
    if (n < N) dinv[n] = rsqrtf((float)cnt[n] + 1.0f);   // deg>=1 (self loop)
}

// ---------------------------------------------------------------------------
// Hierarchical scan.
__global__ __launch_bounds__(256) void scan_phase1(const int* __restrict__ cnt,
                                                   int* __restrict__ blockSums, int N) {
    __shared__ int red[256];
    int base = blockIdx.x * 1024;
    int t = threadIdx.x;
    int s = 0;
    for (int i = 0; i < 4; ++i) {
        int idx = base + t * 4 + i;
        if (idx < N) s += cnt[idx];
    }
    red[t] = s;
    __syncthreads();
    for (int d = 128; d > 0; d >>= 1) {
        if (t < d) red[t] += red[t + d];
        __syncthreads();
    }
    if (t == 0) blockSums[blockIdx.x] = red[0];
}

__global__ __launch_bounds__(256) void scan_phase2(const int* __restrict__ blockSums,
                                                   int* __restrict__ blockOffs,
                                                   int* __restrict__ offs, int B, int N) {
    __shared__ int sh[256];
    int t = threadIdx.x;
    sh[t] = (t < B) ? blockSums[t] : 0;
    __syncthreads();
    for (int d = 1; d < 256; d <<= 1) {
        int v = (t >= d) ? sh[t - d] : 0;
        __syncthreads();
        sh[t] += v;
        __syncthreads();
    }
    if (t < B) blockOffs[t] = (t == 0) ? 0 : sh[t - 1];
    if (t == 255) offs[N] = sh[255];   // == E
}

__global__ __launch_bounds__(256) void scan_phase3(const int* __restrict__ cnt,
                                                   const int* __restrict__ blockOffs,
                                                   int* __restrict__ offs,
                                                   int* __restrict__ cursor, int N) {
    __shared__ int red[256];
    int base = blockIdx.x * 1024;
    int t = threadIdx.x;
    int v[4];
    int s = 0;
    for (int i = 0; i < 4; ++i) {
        int idx = base + t * 4 + i;
        v[i] = (idx < N) ? cnt[idx] : 0;
        s += v[i];
    }
    red[t] = s;
    __syncthreads();
    for (int d = 1; d < 256; d <<= 1) {   // inclusive Hillis-Steele
        int x = (t >= d) ? red[t - d] : 0;
        __syncthreads();
        red[t] += x;
        __syncthreads();
    }
    int run = blockOffs[blockIdx.x] + ((t == 0) ? 0 : red[t - 1]);
    for (int i = 0; i < 4; ++i) {
        int idx = base + t * 4 + i;
        if (idx < N) { offs[idx] = run; cursor[idx] = run; run += v[i]; }
    }
}

// ---------------------------------------------------------------------------
__global__ __launch_bounds__(256) void scatter_kernel(const int* __restrict__ row,
                                                      const int* __restrict__ col,
                                                      const float* __restrict__ dinv,
                                                      int* __restrict__ cursor,
                                                      int2* __restrict__ csr, int E) {
    int e = blockIdx.x * 256 + threadIdx.x;
    if (e >= E) return;
    int r = row[e], c = col[e];
    int pos = atomicAdd(&cursor[c], 1);
    int2 p; p.x = r; p.y = __float_as_int(dinv[r] * dinv[c]);
    csr[pos] = p;
}

// ---------------------------------------------------------------------------
// Split W (fp32 [k][n]) into transposed bf16 hi/lo planes [n][k].
__global__ __launch_bounds__(256) void wconvert(const float* __restrict__ W1,
                                                const float* __restrict__ W2,
                                                unsigned short* __restrict__ Wt1Hi,
                                                unsigned short* __restrict__ Wt1Lo,
                                                unsigned short* __restrict__ Wt2Hi,
                                                unsigned short* __restrict__ Wt2Lo) {
    int i = blockIdx.x * 256 + threadIdx.x;   // 0..32767
    const float* src       = (i < 16384) ? W1    : W2;
    unsigned short* dh     = (i < 16384) ? Wt1Hi : Wt2Hi;
    unsigned short* dl     = (i < 16384) ? Wt1Lo : Wt2Lo;
    int idx = i & 16383;
    int k = idx >> 7, n = idx & 127;
    float v = src[idx];                        // W[k][n]
    unsigned short hb = f2bf_rne(v);
    float hf = __uint_as_float((unsigned int)hb << 16);
    unsigned short lb = f2bf_rne(v - hf);
    dh[n * H_DIM + k] = hb;
    dl[n * H_DIM + k] = lb;
}

// ---------------------------------------------------------------------------
// Layer-1 GEMM: fp32 A (split hi/lo, 3 MFMAs) -> bf16 out.
// Layouts: A[m=lane&15][k=quad*8+j]  B[k=quad*8+j][n=lane&15]  D[row=quad*4+r][col=lane&15]
__global__ __launch_bounds__(256) void gemm_mfma_f32A(const float* __restrict__ X,
                                                      const unsigned short* __restrict__ WtHi,
                                                      const unsigned short* __restrict__ WtLo,
                                                      unsigned short* __restrict__ Yb, int N) {
    int lane = threadIdx.x & 63;
    int wv   = threadIdx.x >> 6;
    int m16  = lane & 15;
    int quad = lane >> 4;
    int nodeBase = blockIdx.x * 32;

    f32x4 acc[2][2] = {};

    #pragma unroll
    for (int kt = 0; kt < 4; ++kt) {
        int k0 = kt * 32 + quad * 8;

        ushort8 aHi[2], aLo[2];
        #pragma unroll
        for (int mi = 0; mi < 2; ++mi) {
            int node = nodeBase + mi * 16 + m16;
            if (node >= N) node = N - 1;
            const float* xp = X + (size_t)node * H_DIM + k0;
            float xv[8];
            *(f32x4*)&xv[0] = *(const f32x4*)xp;
            *(f32x4*)&xv[4] = *(const f32x4*)(xp + 4);
            ushort8 h, l;
            #pragma unroll
            for (int j = 0; j < 8; ++j) {
                unsigned short hb = f2bf_rne(xv[j]);
                float hf = __uint_as_float((unsigned int)hb << 16);
                h[j] = hb;
                l[j] = f2bf_rne(xv[j] - hf);
            }
            aHi[mi] = h; aLo[mi] = l;
        }

        ushort8 bHi[2], bLo[2];
        #pragma unroll
        for (int ni = 0; ni < 2; ++ni) {
            int n = (wv * 2 + ni) * 16 + m16;
            size_t off = (size_t)n * H_DIM + k0;
            bHi[ni] = *(const ushort8*)(WtHi + off);
            bLo[ni] = *(const ushort8*)(WtLo + off);
        }

        #pragma unroll
        for (int mi = 0; mi < 2; ++mi)
            #pragma unroll
            for (int ni = 0; ni < 2; ++ni) {
                acc[mi][ni] = __builtin_amdgcn_mfma_f32_16x16x32_bf16(
                    __builtin_bit_cast(bf16x8, aHi[mi]),
                    __builtin_bit_cast(bf16x8, bHi[ni]), acc[mi][ni], 0, 0, 0);
                acc[mi][ni] = __builtin_amdgcn_mfma_f32_16x16x32_bf16(
                    __builtin_bit_cast(bf16x8, aLo[mi]),
                    __builtin_bit_cast(bf16x8, bHi[ni]), acc[mi][ni], 0, 0, 0);
                acc[mi][ni] = __builtin_amdgcn_mfma_f32_16x16x32_bf16(
                    __builtin_bit_cast(bf16x8, aHi[mi]),
                    __builtin_bit_cast(bf16x8, bLo[ni]), acc[mi][ni], 0, 0, 0);
            }
    }

    #pragma unroll
    for (int mi = 0; mi < 2; ++mi)
        #pragma unroll
        for (int r = 0; r < 4; ++r) {
            int node = nodeBase + mi * 16 + quad * 4 + r;
            if (node < N) {
                #pragma unroll
                for (int ni = 0; ni < 2; ++ni) {
                    int c = (wv * 2 + ni) * 16 + m16;
                    Yb[(size_t)node * H_DIM + c] = f2bf_rne(acc[mi][ni][r]);
                }
            }
        }
}

// ---------------------------------------------------------------------------
// Layer-2 GEMM: bf16 A (exact, 16B loads, 2 MFMAs) -> bf16 out.
__global__ __launch_bounds__(256) void gemm_mfma_bf16A(const unsigned short* __restrict__ Xb,
                                                       const unsigned short* __restrict__ WtHi,
                                                       const unsigned short* __restrict__ WtLo,
                                                       unsigned short* __restrict__ Yb, int N) {
    int lane = threadIdx.x & 63;
    int wv   = threadIdx.x >> 6;
    int m16  = lane & 15;
    int quad = lane >> 4;
    int nodeBase = blockIdx.x * 32;

    f32x4 acc[2][2] = {};

    #pragma unroll
    for (int kt = 0; kt < 4; ++kt) {
        int k0 = kt * 32 + quad * 8;

        ushort8 a[2];
        #pragma unroll
        for (int mi = 0; mi < 2; ++mi) {
            int node = nodeBase + mi * 16 + m16;
            if (node >= N) node = N - 1;
            a[mi] = *(const ushort8*)(Xb + (size_t)node * H_DIM + k0);
        }

        ushort8 bHi[2], bLo[2];
        #pragma unroll
        for (int ni = 0; ni < 2; ++ni) {
            int n = (wv * 2 + ni) * 16 + m16;
            size_t off = (size_t)n * H_DIM + k0;
            bHi[ni] = *(const ushort8*)(WtHi + off);
            bLo[ni] = *(const ushort8*)(WtLo + off);
        }

        #pragma unroll
        for (int mi = 0; mi < 2; ++mi)
            #pragma unroll
            for (int ni = 0; ni < 2; ++ni) {
                acc[mi][ni] = __builtin_amdgcn_mfma_f32_16x16x32_bf16(
                    __builtin_bit_cast(bf16x8, a[mi]),
                    __builtin_bit_cast(bf16x8, bHi[ni]), acc[mi][ni], 0, 0, 0);
                acc[mi][ni] = __builtin_amdgcn_mfma_f32_16x16x32_bf16(
                    __builtin_bit_cast(bf16x8, a[mi]),
                    __builtin_bit_cast(bf16x8, bLo[ni]), acc[mi][ni], 0, 0, 0);
            }
    }

    #pragma unroll
    for (int mi = 0; mi < 2; ++mi)
        #pragma unroll
        for (int r = 0; r < 4; ++r) {
            int node = nodeBase + mi * 16 + quad * 4 + r;
            if (node < N) {
                #pragma unroll
                for (int ni = 0; ni < 2; ++ni) {
                    int c = (wv * 2 + ni) * 16 + m16;
                    Yb[(size_t)node * H_DIM + c] = f2bf_rne(acc[mi][ni][r]);
                }
            }
        }
}

// ---------------------------------------------------------------------------
// One wave per destination node, bf16 gather (uint = 2 bf16 per lane):
// OUT[c,:] = relu( sum_in XWb[r,:]*nrm + XWb[c,:]*dinv[c]^2 + bias ), bf16 out.
__global__ __launch_bounds__(256) void agg_fused(const unsigned short* __restrict__ XWb,
                                                 const float* __restrict__ dinv,
                                                 const int2* __restrict__ csr,
                                                 const int* __restrict__ offs,
                                                 const float* __restrict__ bias,
                                                 unsigned short* __restrict__ OUTb, int N) {
    int wave = (blockIdx.x * 256 + threadIdx.x) >> 6;
    int lane = threadIdx.x & 63;
    if (wave >= N) return;
    int c = wave;
    int start = offs[c], end = offs[c + 1];
    float dc = dinv[c];

    float ax, ay;
    {   // self loop
        unsigned int u = ((const unsigned int*)(XWb + (size_t)c * H_DIM))[lane];
        float s = dc * dc;
        ax = bf_lo(u) * s; ay = bf_hi(u) * s;
    }
    int i = start;
    for (; i + 1 < end; i += 2) {      // 2-way unroll for MLP
        int2 p0 = csr[i];
        int2 p1 = csr[i + 1];
        unsigned int g0 = ((const unsigned int*)(XWb + (size_t)p0.x * H_DIM))[lane];
        unsigned int g1 = ((const unsigned int*)(XWb + (size_t)p1.x * H_DIM))[lane];
        float n0 = __int_as_float(p0.y);
        float n1 = __int_as_float(p1.y);
        ax += bf_lo(g0) * n0; ay += bf_hi(g0) * n0;
        ax += bf_lo(g1) * n1; ay += bf_hi(g1) * n1;
    }
    if (i < end) {
        int2 p = csr[i];
        unsigned int g = ((const unsigned int*)(XWb + (size_t)p.x * H_DIM))[lane];
        float nrm = __int_as_float(p.y);
        ax += bf_lo(g) * nrm; ay += bf_hi(g) * nrm;
    }
    float2 b = ((const float2*)bias)[lane];
    ax = fmaxf(ax + b.x, 0.f);
    ay = fmaxf(ay + b.y, 0.f);
    unsigned int o = (unsigned int)f2bf_rne(ax) | ((unsigned int)f2bf_rne(ay) << 16);
    ((unsigned int*)(OUTb + (size_t)c * H_DIM))[lane] = o;
}

// ---------------------------------------------------------------------------
// Mean pool per graph (batch sorted -> binary-search bounds), bf16 input.
__global__ __launch_bounds__(128) void pool_kernel(const unsigned short* __restrict__ Hb,
                                                   const int* __restrict__ batch,
                                                   float* __restrict__ pooled, int N) {
    __shared__ int bounds[2];
    int g = blockIdx.x;
    if (threadIdx.x < 2) {
        int v = g + (int)threadIdx.x;
        int lo = 0, hi = N;
        while (lo < hi) {
            int mid = (lo + hi) >> 1;
            if (batch[mid] < v) lo = mid + 1; else hi = mid;
        }
        bounds[threadIdx.x] = lo;
    }
    __syncthreads();
    int start = bounds[0], end = bounds[1];
    float s = 0.f;
    for (int n = start; n < end; ++n)
        s += __uint_as_float(((unsigned int)Hb[(size_t)n * H_DIM + threadIdx.x]) << 16);
    int cnt = end - start;
    pooled[g * H_DIM + threadIdx.x] = s / (float)(cnt > 0 ? cnt : 1);
}

// ---------------------------------------------------------------------------
__global__ __launch_bounds__(64) void head_kernel(const float* __restrict__ pooled,
                                                  const float* __restrict__ Wfc,
                                                  const float* __restrict__ bfc,
                                                  float* __restrict__ out) {
    __shared__ float sl[OUT_DIM + 2];
    int g = blockIdx.x;
    int j = threadIdx.x;
    if (j < OUT_DIM) {
        float acc = bfc[j];
        const float* p = pooled + g * H_DIM;
        for (int k = 0; k < H_DIM; ++k) acc += p[k] * Wfc[k * OUT_DIM + j];
        sl[j] = acc;
    }
    __syncthreads();
    if (j == 0) {
        float m = sl[0];
        for (int i = 1; i < OUT_DIM; ++i) m = fmaxf(m, sl[i]);
        float s = 0.f;
        for (int i = 0; i < OUT_DIM; ++i) s += expf(sl[i] - m);
        sl[OUT_DIM] = m + logf(s);
    }
    __syncthreads();
    if (j < OUT_DIM) out[g * OUT_DIM + j] = sl[j] - sl[OUT_DIM];
}

// ---------------------------------------------------------------------------
extern "C" void kernel_launch(void* const* d_in, const int* in_sizes, int n_in,
                              void* d_out, int out_size, void* d_ws, size_t ws_size,
                              hipStream_t stream) {
    const float* x     = (const float*)d_in[0];
    const int*   ei    = (const int*)  d_in[1];
    const int*   batch = (const int*)  d_in[2];
    const float* W1    = (const float*)d_in[3];
    const float* b1    = (const float*)d_in[4];
    const float* W2    = (const float*)d_in[5];
    const float* b2    = (const float*)d_in[6];
    const float* Wfc   = (const float*)d_in[7];
    const float* bfc   = (const float*)d_in[8];
    float* out = (float*)d_out;

    int N = in_sizes[2];
    int E = in_sizes[1] / 2;
    int G = out_size / OUT_DIM;
    const int* row = ei;
    const int* col = ei + E;

    // Workspace layout:
    // cnt[N] | offs[N+1] | cursor[N] | dinv[N] (int/f32, nAlign each) | csr[E] int2
    //   | Xb[N*128] ushort | Hb[N*128] ushort | pooled[G*128] f32
    //   | blockSums[256] | blockOffs[256] | Wt{1,2}{Hi,Lo}[128*128] ushort
    char* wsb = (char*)d_ws;
    size_t nAlign = (size_t)((N + 256) / 256) * 256;   // >= N+1
    int*   cnt    = (int*)wsb;
    int*   offs   = cnt + nAlign;
    int*   cursor = offs + nAlign;
    float* dinv   = (float*)(cursor + nAlign);
    int2*  csr    = (int2*)(dinv + nAlign);
    unsigned short* Xb = (unsigned short*)(csr + E);
    unsigned short* Hb = Xb + (size_t)N * H_DIM;
    float* pooled = (float*)(Hb + (size_t)N * H_DIM);
    int* blockSums = (int*)(pooled + (size_t)G * H_DIM);
    int* blockOffs = blockSums + 256;
    unsigned short* Wt1Hi = (unsigned short*)(blockOffs + 256);
    unsigned short* Wt1Lo = Wt1Hi + H_DIM * H_DIM;
    unsigned short* Wt2Hi = Wt1Lo + H_DIM * H_DIM;
    unsigned short* Wt2Lo = Wt2Hi + H_DIM * H_DIM;

    int scanBlocks = (N + 1023) / 1024;   // 40 for N=40000 (<=256 supported)

    // ---- W split/transpose for MFMA
    wconvert<<<128, 256, 0, stream>>>(W1, W2, Wt1Hi, Wt1Lo, Wt2Hi, Wt2Lo);

    // ---- Build dinv + CSR (by destination col)
    hipMemsetAsync(cnt, 0, N * sizeof(int), stream);
    hist_kernel<<<(E + 255) / 256, 256, 0, stream>>>(col, cnt, E);
    dinv_kernel<<<(N + 255) / 256, 256, 0, stream>>>(cnt, dinv, N);
    scan_phase1<<<scanBlocks, 256, 0, stream>>>(cnt, blockSums, N);
    scan_phase2<<<1, 256, 0, stream>>>(blockSums, blockOffs, offs, scanBlocks, N);
    scan_phase3<<<scanBlocks, 256, 0, stream>>>(cnt, blockOffs, offs, cursor, N);
    scatter_kernel<<<(E + 255) / 256, 256, 0, stream>>>(row, col, dinv, cursor, csr, E);

    int aggBlocks  = (N + 3) / 4;     // 4 waves/block, 1 wave/node
    int gemmBlocks = (N + 31) / 32;   // 32 nodes/block

    // ---- Layer 1
    gemm_mfma_f32A<<<gemmBlocks, 256, 0, stream>>>(x, Wt1Hi, Wt1Lo, Xb, N);
    agg_fused<<<aggBlocks, 256, 0, stream>>>(Xb, dinv, csr, offs, b1, Hb, N);

    // ---- Layer 2 (reuse Xb for XW2)
    gemm_mfma_bf16A<<<gemmBlocks, 256, 0, stream>>>(Hb, Wt2Hi, Wt2Lo, Xb, N);
    agg_fused<<<aggBlocks, 256, 0, stream>>>(Xb, dinv, csr, offs, b2, Hb, N);

    // ---- Pool + head
    pool_kernel<<<G, 128, 0, stream>>>(Hb, batch, pooled, N);
    head_kernel<<<G, 64, 0, stream>>>(pooled, Wfc, bfc, out);
}

// Round 6
// 303.586 us; speedup vs baseline: 4.5291x; 1.0887x over previous
//
#include <hip/hip_runtime.h>
#include <math.h>

#define H_DIM 128
#define OUT_DIM 10

typedef __attribute__((ext_vector_type(8))) __bf16 bf16x8;
typedef __attribute__((ext_vector_type(8))) unsigned short ushort8;
typedef __attribute__((ext_vector_type(4))) float f32x4;

__device__ inline unsigned short f2bf_rne(float f) {
    unsigned int u = __float_as_uint(f);
    unsigned int r = u + 0x7FFFu + ((u >> 16) & 1u);
    return (unsigned short)(r >> 16);
}
__device__ inline float bf_lo(unsigned int u) { return __uint_as_float(u << 16); }
__device__ inline float bf_hi(unsigned int u) { return __uint_as_float(u & 0xFFFF0000u); }

// ---------------------------------------------------------------------------
__global__ __launch_bounds__(256) void hist_kernel(const int* __restrict__ col,
                                                   int* __restrict__ cnt, int E) {
    int e = blockIdx.x * 256 + threadIdx.x;
    if (e < E) atomicAdd(&cnt[col[e]], 1);
}

__global__ __launch_bounds__(256) void dinv_kernel(const int* __restrict__ cnt,
                                                   float* __restrict__ dinv, int N) {
    int n = blockIdx.x * 256 + threadIdx.x;
    if (n < N) dinv[n] = rsqrtf((float)cnt[n] + 1.0f);   // deg>=1 (self loop)
}

// ---------------------------------------------------------------------------
// Hierarchical scan.
__global__ __launch_bounds__(256) void scan_phase1(const int* __restrict__ cnt,
                                                   int* __restrict__ blockSums, int N) {
    __shared__ int red[256];
    int base = blockIdx.x * 1024;
    int t = threadIdx.x;
    int s = 0;
    for (int i = 0; i < 4; ++i) {
        int idx = base + t * 4 + i;
        if (idx < N) s += cnt[idx];
    }
    red[t] = s;
    __syncthreads();
    for (int d = 128; d > 0; d >>= 1) {
        if (t < d) red[t] += red[t + d];
        __syncthreads();
    }
    if (t == 0) blockSums[blockIdx.x] = red[0];
}

__global__ __launch_bounds__(256) void scan_phase2(const int* __restrict__ blockSums,
                                                   int* __restrict__ blockOffs,
                                                   int* __restrict__ offs, int B, int N) {
    __shared__ int sh[256];
    int t = threadIdx.x;
    sh[t] = (t < B) ? blockSums[t] : 0;
    __syncthreads();
    for (int d = 1; d < 256; d <<= 1) {
        int v = (t >= d) ? sh[t - d] : 0;
        __syncthreads();
        sh[t] += v;
        __syncthreads();
    }
    if (t < B) blockOffs[t] = (t == 0) ? 0 : sh[t - 1];
    if (t == 255) offs[N] = sh[255];   // == E
}

__global__ __launch_bounds__(256) void scan_phase3(const int* __restrict__ cnt,
                                                   const int* __restrict__ blockOffs,
                                                   int* __restrict__ offs,
                                                   int* __restrict__ cursor, int N) {
    __shared__ int red[256];
    int base = blockIdx.x * 1024;
    int t = threadIdx.x;
    int v[4];
    int s = 0;
    for (int i = 0; i < 4; ++i) {
        int idx = base + t * 4 + i;
        v[i] = (idx < N) ? cnt[idx] : 0;
        s += v[i];
    }
    red[t] = s;
    __syncthreads();
    for (int d = 1; d < 256; d <<= 1) {   // inclusive Hillis-Steele
        int x = (t >= d) ? red[t - d] : 0;
        __syncthreads();
        red[t] += x;
        __syncthreads();
    }
    int run = blockOffs[blockIdx.x] + ((t == 0) ? 0 : red[t - 1]);
    for (int i = 0; i < 4; ++i) {
        int idx = base + t * 4 + i;
        if (idx < N) { offs[idx] = run; cursor[idx] = run; run += v[i]; }
    }
}

// ---------------------------------------------------------------------------
__global__ __launch_bounds__(256) void scatter_kernel(const int* __restrict__ row,
                                                      const int* __restrict__ col,
                                                      const float* __restrict__ dinv,
                                                      int* __restrict__ cursor,
                                                      int2* __restrict__ csr, int E) {
    int e = blockIdx.x * 256 + threadIdx.x;
    if (e >= E) return;
    int r = row[e], c = col[e];
    int pos = atomicAdd(&cursor[c], 1);
    int2 p; p.x = r; p.y = __float_as_int(dinv[r] * dinv[c]);
    csr[pos] = p;
}

// ---------------------------------------------------------------------------
// Split W (fp32 [k][n]) into transposed bf16 hi/lo planes [n][k].
__global__ __launch_bounds__(256) void wconvert(const float* __restrict__ W1,
                                                const float* __restrict__ W2,
                                                unsigned short* __restrict__ Wt1Hi,
                                                unsigned short* __restrict__ Wt1Lo,
                                                unsigned short* __restrict__ Wt2Hi,
                                                unsigned short* __restrict__ Wt2Lo) {
    int i = blockIdx.x * 256 + threadIdx.x;   // 0..32767
    const float* src       = (i < 16384) ? W1    : W2;
    unsigned short* dh     = (i < 16384) ? Wt1Hi : Wt2Hi;
    unsigned short* dl     = (i < 16384) ? Wt1Lo : Wt2Lo;
    int idx = i & 16383;
    int k = idx >> 7, n = idx & 127;
    float v = src[idx];                        // W[k][n]
    unsigned short hb = f2bf_rne(v);
    float hf = __uint_as_float((unsigned int)hb << 16);
    unsigned short lb = f2bf_rne(v - hf);
    dh[n * H_DIM + k] = hb;
    dl[n * H_DIM + k] = lb;
}

// ---------------------------------------------------------------------------
// Layer-1 GEMM: fp32 A (split hi/lo, 3 MFMAs) -> bf16 out.
// Layouts: A[m=lane&15][k=quad*8+j]  B[k=quad*8+j][n=lane&15]  D[row=quad*4+r][col=lane&15]
__global__ __launch_bounds__(256) void gemm_mfma_f32A(const float* __restrict__ X,
                                                      const unsigned short* __restrict__ WtHi,
                                                      const unsigned short* __restrict__ WtLo,
                                                      unsigned short* __restrict__ Yb, int N) {
    int lane = threadIdx.x & 63;
    int wv   = threadIdx.x >> 6;
    int m16  = lane & 15;
    int quad = lane >> 4;
    int nodeBase = blockIdx.x * 32;

    f32x4 acc[2][2] = {};

    #pragma unroll
    for (int kt = 0; kt < 4; ++kt) {
        int k0 = kt * 32 + quad * 8;

        ushort8 aHi[2], aLo[2];
        #pragma unroll
        for (int mi = 0; mi < 2; ++mi) {
            int node = nodeBase + mi * 16 + m16;
            if (node >= N) node = N - 1;
            const float* xp = X + (size_t)node * H_DIM + k0;
            float xv[8];
            *(f32x4*)&xv[0] = *(const f32x4*)xp;
            *(f32x4*)&xv[4] = *(const f32x4*)(xp + 4);
            ushort8 h, l;
            #pragma unroll
            for (int j = 0; j < 8; ++j) {
                unsigned short hb = f2bf_rne(xv[j]);
                float hf = __uint_as_float((unsigned int)hb << 16);
                h[j] = hb;
                l[j] = f2bf_rne(xv[j] - hf);
            }
            aHi[mi] = h; aLo[mi] = l;
        }

        ushort8 bHi[2], bLo[2];
        #pragma unroll
        for (int ni = 0; ni < 2; ++ni) {
            int n = (wv * 2 + ni) * 16 + m16;
            size_t off = (size_t)n * H_DIM + k0;
            bHi[ni] = *(const ushort8*)(WtHi + off);
            bLo[ni] = *(const ushort8*)(WtLo + off);
        }

        #pragma unroll
        for (int mi = 0; mi < 2; ++mi)
            #pragma unroll
            for (int ni = 0; ni < 2; ++ni) {
                acc[mi][ni] = __builtin_amdgcn_mfma_f32_16x16x32_bf16(
                    __builtin_bit_cast(bf16x8, aHi[mi]),
                    __builtin_bit_cast(bf16x8, bHi[ni]), acc[mi][ni], 0, 0, 0);
                acc[mi][ni] = __builtin_amdgcn_mfma_f32_16x16x32_bf16(
                    __builtin_bit_cast(bf16x8, aLo[mi]),
                    __builtin_bit_cast(bf16x8, bHi[ni]), acc[mi][ni], 0, 0, 0);
                acc[mi][ni] = __builtin_amdgcn_mfma_f32_16x16x32_bf16(
                    __builtin_bit_cast(bf16x8, aHi[mi]),
                    __builtin_bit_cast(bf16x8, bLo[ni]), acc[mi][ni], 0, 0, 0);
            }
    }

    #pragma unroll
    for (int mi = 0; mi < 2; ++mi)
        #pragma unroll
        for (int r = 0; r < 4; ++r) {
            int node = nodeBase + mi * 16 + quad * 4 + r;
            if (node < N) {
                #pragma unroll
                for (int ni = 0; ni < 2; ++ni) {
                    int c = (wv * 2 + ni) * 16 + m16;
                    Yb[(size_t)node * H_DIM + c] = f2bf_rne(acc[mi][ni][r]);
                }
            }
        }
}

// ---------------------------------------------------------------------------
// Layer-2 GEMM: bf16 A (exact, 16B loads, 2 MFMAs) -> bf16 out.
__global__ __launch_bounds__(256) void gemm_mfma_bf16A(const unsigned short* __restrict__ Xb,
                                                       const unsigned short* __restrict__ WtHi,
                                                       const unsigned short* __restrict__ WtLo,
                                                       unsigned short* __restrict__ Yb, int N) {
    int lane = threadIdx.x & 63;
    int wv   = threadIdx.x >> 6;
    int m16  = lane & 15;
    int quad = lane >> 4;
    int nodeBase = blockIdx.x * 32;

    f32x4 acc[2][2] = {};

    #pragma unroll
    for (int kt = 0; kt < 4; ++kt) {
        int k0 = kt * 32 + quad * 8;

        ushort8 a[2];
        #pragma unroll
        for (int mi = 0; mi < 2; ++mi) {
            int node = nodeBase + mi * 16 + m16;
            if (node >= N) node = N - 1;
            a[mi] = *(const ushort8*)(Xb + (size_t)node * H_DIM + k0);
        }

        ushort8 bHi[2], bLo[2];
        #pragma unroll
        for (int ni = 0; ni < 2; ++ni) {
            int n = (wv * 2 + ni) * 16 + m16;
            size_t off = (size_t)n * H_DIM + k0;
            bHi[ni] = *(const ushort8*)(WtHi + off);
            bLo[ni] = *(const ushort8*)(WtLo + off);
        }

        #pragma unroll
        for (int mi = 0; mi < 2; ++mi)
            #pragma unroll
            for (int ni = 0; ni < 2; ++ni) {
                acc[mi][ni] = __builtin_amdgcn_mfma_f32_16x16x32_bf16(
                    __builtin_bit_cast(bf16x8, a[mi]),
                    __builtin_bit_cast(bf16x8, bHi[ni]), acc[mi][ni], 0, 0, 0);
                acc[mi][ni] = __builtin_amdgcn_mfma_f32_16x16x32_bf16(
                    __builtin_bit_cast(bf16x8, a[mi]),
                    __builtin_bit_cast(bf16x8, bLo[ni]), acc[mi][ni], 0, 0, 0);
            }
    }

    #pragma unroll
    for (int mi = 0; mi < 2; ++mi)
        #pragma unroll
        for (int r = 0; r < 4; ++r) {
            int node = nodeBase + mi * 16 + quad * 4 + r;
            if (node < N) {
                #pragma unroll
                for (int ni = 0; ni < 2; ++ni) {
                    int c = (wv * 2 + ni) * 16 + m16;
                    Yb[(size_t)node * H_DIM + c] = f2bf_rne(acc[mi][ni][r]);
                }
            }
        }
}

// ---------------------------------------------------------------------------
// One wave per destination node, bf16 gather (uint = 2 bf16 per lane):
// OUT[c,:] = relu( sum_in XWb[r,:]*nrm + XWb[c,:]*dinv[c]^2 + bias ), bf16 out.
__global__ __launch_bounds__(256) void agg_fused(const unsigned short* __restrict__ XWb,
                                                 const float* __restrict__ dinv,
                                                 const int2* __restrict__ csr,
                                                 const int* __restrict__ offs,
                                                 const float* __restrict__ bias,
                                                 unsigned short* __restrict__ OUTb, int N) {
    int wave = (blockIdx.x * 256 + threadIdx.x) >> 6;
    int lane = threadIdx.x & 63;
    if (wave >= N) return;
    int c = wave;
    int start = offs[c], end = offs[c + 1];
    float dc = dinv[c];

    float ax, ay;
    {   // self loop
        unsigned int u = ((const unsigned int*)(XWb + (size_t)c * H_DIM))[lane];
        float s = dc * dc;
        ax = bf_lo(u) * s; ay = bf_hi(u) * s;
    }
    int i = start;
    for (; i + 1 < end; i += 2) {      // 2-way unroll for MLP
        int2 p0 = csr[i];
        int2 p1 = csr[i + 1];
        unsigned int g0 = ((const unsigned int*)(XWb + (size_t)p0.x * H_DIM))[lane];
        unsigned int g1 = ((const unsigned int*)(XWb + (size_t)p1.x * H_DIM))[lane];
        float n0 = __int_as_float(p0.y);
        float n1 = __int_as_float(p1.y);
        ax += bf_lo(g0) * n0; ay += bf_hi(g0) * n0;
        ax += bf_lo(g1) * n1; ay += bf_hi(g1) * n1;
    }
    if (i < end) {
        int2 p = csr[i];
        unsigned int g = ((const unsigned int*)(XWb + (size_t)p.x * H_DIM))[lane];
        float nrm = __int_as_float(p.y);
        ax += bf_lo(g) * nrm; ay += bf_hi(g) * nrm;
    }
    float2 b = ((const float2*)bias)[lane];
    ax = fmaxf(ax + b.x, 0.f);
    ay = fmaxf(ay + b.y, 0.f);
    unsigned int o = (unsigned int)f2bf_rne(ax) | ((unsigned int)f2bf_rne(ay) << 16);
    ((unsigned int*)(OUTb + (size_t)c * H_DIM))[lane] = o;
}

// ---------------------------------------------------------------------------
// Pooling phase 1: partial sums.  64 nodes/block, 256 threads:
// thread = (feature f = t&127, subrange sub = t>>7 covering 32 nodes).
// Local accumulate, flush one atomicAdd per graph-boundary crossing.
__global__ __launch_bounds__(256) void pool_partial(const unsigned short* __restrict__ Hb,
                                                    const int* __restrict__ batch,
                                                    float* __restrict__ pooledSum, int N) {
    __shared__ int sb[64];
    int base = blockIdx.x * 64;
    int t = threadIdx.x;
    if (t < 64) {
        int idx = base + t;
        sb[t] = (idx < N) ? batch[idx] : -1;
    }
    __syncthreads();
    int f   = t & 127;
    int sub = t >> 7;            // 0..1
    int n0  = sub * 32;
    float acc = 0.f;
    int curg = -1;
    #pragma unroll 4
    for (int i = 0; i < 32; ++i) {
        int n = base + n0 + i;
        if (n >= N) break;
        int g = sb[n0 + i];
        if (g != curg) {
            if (curg >= 0) atomicAdd(&pooledSum[curg * H_DIM + f], acc);
            acc = 0.f; curg = g;
        }
        acc += __uint_as_float(((unsigned int)Hb[(size_t)n * H_DIM + f]) << 16);
    }
    if (curg >= 0) atomicAdd(&pooledSum[curg * H_DIM + f], acc);
}

// ---------------------------------------------------------------------------
// Head: count via binary search on sorted batch, mean, FC, log-softmax.
__global__ __launch_bounds__(64) void head_kernel(const float* __restrict__ pooledSum,
                                                  const int* __restrict__ batch,
                                                  const float* __restrict__ Wfc,
                                                  const float* __restrict__ bfc,
                                                  float* __restrict__ out, int N) {
    __shared__ float sl[OUT_DIM + 2];
    __shared__ int bounds[2];
    int g = blockIdx.x;
    int j = threadIdx.x;
    if (j < 2) {
        int v = g + j;
        int lo = 0, hi = N;
        while (lo < hi) {
            int mid = (lo + hi) >> 1;
            if (batch[mid] < v) lo = mid + 1; else hi = mid;
        }
        bounds[j] = lo;
    }
    __syncthreads();
    int cnt = bounds[1] - bounds[0];
    float inv = 1.0f / (float)(cnt > 0 ? cnt : 1);
    if (j < OUT_DIM) {
        float acc = 0.f;
        const float* p = pooledSum + g * H_DIM;
        for (int k = 0; k < H_DIM; ++k) acc += p[k] * Wfc[k * OUT_DIM + j];
        sl[j] = acc * inv + bfc[j];
    }
    __syncthreads();
    if (j == 0) {
        float m = sl[0];
        for (int i = 1; i < OUT_DIM; ++i) m = fmaxf(m, sl[i]);
        float s = 0.f;
        for (int i = 0; i < OUT_DIM; ++i) s += expf(sl[i] - m);
        sl[OUT_DIM] = m + logf(s);
    }
    __syncthreads();
    if (j < OUT_DIM) out[g * OUT_DIM + j] = sl[j] - sl[OUT_DIM];
}

// ---------------------------------------------------------------------------
extern "C" void kernel_launch(void* const* d_in, const int* in_sizes, int n_in,
                              void* d_out, int out_size, void* d_ws, size_t ws_size,
                              hipStream_t stream) {
    const float* x     = (const float*)d_in[0];
    const int*   ei    = (const int*)  d_in[1];
    const int*   batch = (const int*)  d_in[2];
    const float* W1    = (const float*)d_in[3];
    const float* b1    = (const float*)d_in[4];
    const float* W2    = (const float*)d_in[5];
    const float* b2    = (const float*)d_in[6];
    const float* Wfc   = (const float*)d_in[7];
    const float* bfc   = (const float*)d_in[8];
    float* out = (float*)d_out;

    int N = in_sizes[2];
    int E = in_sizes[1] / 2;
    int G = out_size / OUT_DIM;
    const int* row = ei;
    const int* col = ei + E;

    // Workspace layout:
    // cnt[N] | offs[N+1] | cursor[N] | dinv[N] (nAlign each) | csr[E] int2
    //   | Xb[N*128] ushort | Hb[N*128] ushort | pooledSum[G*128] f32
    //   | blockSums[256] | blockOffs[256] | Wt{1,2}{Hi,Lo}[128*128] ushort
    char* wsb = (char*)d_ws;
    size_t nAlign = (size_t)((N + 256) / 256) * 256;   // >= N+1
    int*   cnt    = (int*)wsb;
    int*   offs   = cnt + nAlign;
    int*   cursor = offs + nAlign;
    float* dinv   = (float*)(cursor + nAlign);
    int2*  csr    = (int2*)(dinv + nAlign);
    unsigned short* Xb = (unsigned short*)(csr + E);
    unsigned short* Hb = Xb + (size_t)N * H_DIM;
    float* pooledSum = (float*)(Hb + (size_t)N * H_DIM);
    int* blockSums = (int*)(pooledSum + (size_t)G * H_DIM);
    int* blockOffs = blockSums + 256;
    unsigned short* Wt1Hi = (unsigned short*)(blockOffs + 256);
    unsigned short* Wt1Lo = Wt1Hi + H_DIM * H_DIM;
    unsigned short* Wt2Hi = Wt1Lo + H_DIM * H_DIM;
    unsigned short* Wt2Lo = Wt2Hi + H_DIM * H_DIM;

    int scanBlocks = (N + 1023) / 1024;   // 40 for N=40000 (<=256 supported)

    // ---- W split/transpose for MFMA
    wconvert<<<128, 256, 0, stream>>>(W1, W2, Wt1Hi, Wt1Lo, Wt2Hi, Wt2Lo);

    // ---- Build dinv + CSR (by destination col)
    hipMemsetAsync(cnt, 0, N * sizeof(int), stream);
    hist_kernel<<<(E + 255) / 256, 256, 0, stream>>>(col, cnt, E);
    dinv_kernel<<<(N + 255) / 256, 256, 0, stream>>>(cnt, dinv, N);
    scan_phase1<<<scanBlocks, 256, 0, stream>>>(cnt, blockSums, N);
    scan_phase2<<<1, 256, 0, stream>>>(blockSums, blockOffs, offs, scanBlocks, N);
    scan_phase3<<<scanBlocks, 256, 0, stream>>>(cnt, blockOffs, offs, cursor, N);
    scatter_kernel<<<(E + 255) / 256, 256, 0, stream>>>(row, col, dinv, cursor, csr, E);

    int aggBlocks  = (N + 3) / 4;     // 4 waves/block, 1 wave/node
    int gemmBlocks = (N + 31) / 32;   // 32 nodes/block

    // ---- Layer 1
    gemm_mfma_f32A<<<gemmBlocks, 256, 0, stream>>>(x, Wt1Hi, Wt1Lo, Xb, N);
    agg_fused<<<aggBlocks, 256, 0, stream>>>(Xb, dinv, csr, offs, b1, Hb, N);

    // ---- Layer 2 (reuse Xb for XW2)
    gemm_mfma_bf16A<<<gemmBlocks, 256, 0, stream>>>(Hb, Wt2Hi, Wt2Lo, Xb, N);
    agg_fused<<<aggBlocks, 256, 0, stream>>>(Xb, dinv, csr, offs, b2, Hb, N);

    // ---- Pool (partial sums + atomics) + head (count/divide folded in)
    hipMemsetAsync(pooledSum, 0, (size_t)G * H_DIM * sizeof(float), stream);
    pool_partial<<<(N + 63) / 64, 256, 0, stream>>>(Hb, batch, pooledSum, N);
    head_kernel<<<G, 64, 0, stream>>>(pooledSum, batch, Wfc, bfc, out, N);
}

// Round 7
// 289.797 us; speedup vs baseline: 4.7446x; 1.0476x over previous
//
#include <hip/hip_runtime.h>
#include <math.h>

#define H_DIM 128
#define OUT_DIM 10

typedef __attribute__((ext_vector_type(8))) __bf16 bf16x8;
typedef __attribute__((ext_vector_type(8))) unsigned short ushort8;
typedef __attribute__((ext_vector_type(4))) float f32x4;

__device__ inline unsigned short f2bf_rne(float f) {
    unsigned int u = __float_as_uint(f);
    unsigned int r = u + 0x7FFFu + ((u >> 16) & 1u);
    return (unsigned short)(r >> 16);
}
__device__ inline float bf_lo(unsigned int u) { return __uint_as_float(u << 16); }
__device__ inline float bf_hi(unsigned int u) { return __uint_as_float(u & 0xFFFF0000u); }

// ---------------------------------------------------------------------------
__global__ __launch_bounds__(256) void hist_kernel(const int* __restrict__ col,
                                                   int* __restrict__ cnt, int E) {
    int e = blockIdx.x * 256 + threadIdx.x;
    if (e < E) atomicAdd(&cnt[col[e]], 1);
}

__global__ __launch_bounds__(256) void dinv_kernel(const int* __restrict__ cnt,
                                                   float* __restrict__ dinv, int N) {
    int n = blockIdx.x * 256 + threadIdx.x;
    if (n < N) dinv[n] = rsqrtf((float)cnt[n] + 1.0f);   // deg>=1 (self loop)
}

// ---------------------------------------------------------------------------
// Hierarchical scan.
__global__ __launch_bounds__(256) void scan_phase1(const int* __restrict__ cnt,
                                                   int* __restrict__ blockSums, int N) {
    __shared__ int red[256];
    int base = blockIdx.x * 1024;
    int t = threadIdx.x;
    int s = 0;
    for (int i = 0; i < 4; ++i) {
        int idx = base + t * 4 + i;
        if (idx < N) s += cnt[idx];
    }
    red[t] = s;
    __syncthreads();
    for (int d = 128; d > 0; d >>= 1) {
        if (t < d) red[t] += red[t + d];
        __syncthreads();
    }
    if (t == 0) blockSums[blockIdx.x] = red[0];
}

__global__ __launch_bounds__(256) void scan_phase2(const int* __restrict__ blockSums,
                                                   int* __restrict__ blockOffs,
                                                   int* __restrict__ offs, int B, int N) {
    __shared__ int sh[256];
    int t = threadIdx.x;
    sh[t] = (t < B) ? blockSums[t] : 0;
    __syncthreads();
    for (int d = 1; d < 256; d <<= 1) {
        int v = (t >= d) ? sh[t - d] : 0;
        __syncthreads();
        sh[t] += v;
        __syncthreads();
    }
    if (t < B) blockOffs[t] = (t == 0) ? 0 : sh[t - 1];
    if (t == 255) offs[N] = sh[255];   // == E
}

__global__ __launch_bounds__(256) void scan_phase3(const int* __restrict__ cnt,
                                                   const int* __restrict__ blockOffs,
                                                   int* __restrict__ offs,
                                                   int* __restrict__ cursor, int N) {
    __shared__ int red[256];
    int base = blockIdx.x * 1024;
    int t = threadIdx.x;
    int v[4];
    int s = 0;
    for (int i = 0; i < 4; ++i) {
        int idx = base + t * 4 + i;
        v[i] = (idx < N) ? cnt[idx] : 0;
        s += v[i];
    }
    red[t] = s;
    __syncthreads();
    for (int d = 1; d < 256; d <<= 1) {   // inclusive Hillis-Steele
        int x = (t >= d) ? red[t - d] : 0;
        __syncthreads();
        red[t] += x;
        __syncthreads();
    }
    int run = blockOffs[blockIdx.x] + ((t == 0) ? 0 : red[t - 1]);
    for (int i = 0; i < 4; ++i) {
        int idx = base + t * 4 + i;
        if (idx < N) { offs[idx] = run; cursor[idx] = run; run += v[i]; }
    }
}

// ---------------------------------------------------------------------------
__global__ __launch_bounds__(256) void scatter_kernel(const int* __restrict__ row,
                                                      const int* __restrict__ col,
                                                      const float* __restrict__ dinv,
                                                      int* __restrict__ cursor,
                                                      int2* __restrict__ csr, int E) {
    int e = blockIdx.x * 256 + threadIdx.x;
    if (e >= E) return;
    int r = row[e], c = col[e];
    int pos = atomicAdd(&cursor[c], 1);
    int2 p; p.x = r; p.y = __float_as_int(dinv[r] * dinv[c]);
    csr[pos] = p;
}

// ---------------------------------------------------------------------------
// Split W (fp32 [k][n]) into transposed bf16 hi/lo planes [n][k].
__global__ __launch_bounds__(256) void wconvert(const float* __restrict__ W1,
                                                const float* __restrict__ W2,
                                                unsigned short* __restrict__ Wt1Hi,
                                                unsigned short* __restrict__ Wt1Lo,
                                                unsigned short* __restrict__ Wt2Hi,
                                                unsigned short* __restrict__ Wt2Lo) {
    int i = blockIdx.x * 256 + threadIdx.x;   // 0..32767
    const float* src       = (i < 16384) ? W1    : W2;
    unsigned short* dh     = (i < 16384) ? Wt1Hi : Wt2Hi;
    unsigned short* dl     = (i < 16384) ? Wt1Lo : Wt2Lo;
    int idx = i & 16383;
    int k = idx >> 7, n = idx & 127;
    float v = src[idx];                        // W[k][n]
    unsigned short hb = f2bf_rne(v);
    float hf = __uint_as_float((unsigned int)hb << 16);
    unsigned short lb = f2bf_rne(v - hf);
    dh[n * H_DIM + k] = hb;
    dl[n * H_DIM + k] = lb;
}

// ---------------------------------------------------------------------------
// Split X (fp32, row-major [N,128]) into bf16 hi/lo planes (same layout).
// 8 elements per thread, fully vectorized.
__global__ __launch_bounds__(256) void xsplit(const float* __restrict__ X,
                                              unsigned short* __restrict__ Xhi,
                                              unsigned short* __restrict__ Xlo,
                                              int total8) {
    int i = blockIdx.x * 256 + threadIdx.x;
    if (i >= total8) return;
    const float* p = X + (size_t)i * 8;
    f32x4 a = *(const f32x4*)p;
    f32x4 b = *(const f32x4*)(p + 4);
    float v[8] = {a.x, a.y, a.z, a.w, b.x, b.y, b.z, b.w};
    ushort8 h, l;
    #pragma unroll
    for (int j = 0; j < 8; ++j) {
        unsigned short hb = f2bf_rne(v[j]);
        float hf = __uint_as_float((unsigned int)hb << 16);
        h[j] = hb;
        l[j] = f2bf_rne(v[j] - hf);
    }
    *(ushort8*)(Xhi + (size_t)i * 8) = h;
    *(ushort8*)(Xlo + (size_t)i * 8) = l;
}

// ---------------------------------------------------------------------------
// Layer-1 GEMM: pre-split bf16 A planes (hi/lo), 3 MFMAs/tile -> bf16 out.
// Layouts: A[m=lane&15][k=quad*8+j]  B[k=quad*8+j][n=lane&15]  D[row=quad*4+r][col=lane&15]
__global__ __launch_bounds__(256) void gemm_mfma_splitA(const unsigned short* __restrict__ Ahi,
                                                        const unsigned short* __restrict__ Alo,
                                                        const unsigned short* __restrict__ WtHi,
                                                        const unsigned short* __restrict__ WtLo,
                                                        unsigned short* __restrict__ Yb, int N) {
    int lane = threadIdx.x & 63;
    int wv   = threadIdx.x >> 6;
    int m16  = lane & 15;
    int quad = lane >> 4;
    int nodeBase = blockIdx.x * 32;

    f32x4 acc[2][2] = {};

    #pragma unroll
    for (int kt = 0; kt < 4; ++kt) {
        int k0 = kt * 32 + quad * 8;

        ushort8 aHi[2], aLo[2];
        #pragma unroll
        for (int mi = 0; mi < 2; ++mi) {
            int node = nodeBase + mi * 16 + m16;
            if (node >= N) node = N - 1;
            size_t off = (size_t)node * H_DIM + k0;
            aHi[mi] = *(const ushort8*)(Ahi + off);
            aLo[mi] = *(const ushort8*)(Alo + off);
        }

        ushort8 bHi[2], bLo[2];
        #pragma unroll
        for (int ni = 0; ni < 2; ++ni) {
            int n = (wv * 2 + ni) * 16 + m16;
            size_t off = (size_t)n * H_DIM + k0;
            bHi[ni] = *(const ushort8*)(WtHi + off);
            bLo[ni] = *(const ushort8*)(WtLo + off);
        }

        #pragma unroll
        for (int mi = 0; mi < 2; ++mi)
            #pragma unroll
            for (int ni = 0; ni < 2; ++ni) {
                acc[mi][ni] = __builtin_amdgcn_mfma_f32_16x16x32_bf16(
                    __builtin_bit_cast(bf16x8, aHi[mi]),
                    __builtin_bit_cast(bf16x8, bHi[ni]), acc[mi][ni], 0, 0, 0);
                acc[mi][ni] = __builtin_amdgcn_mfma_f32_16x16x32_bf16(
                    __builtin_bit_cast(bf16x8, aLo[mi]),
                    __builtin_bit_cast(bf16x8, bHi[ni]), acc[mi][ni], 0, 0, 0);
                acc[mi][ni] = __builtin_amdgcn_mfma_f32_16x16x32_bf16(
                    __builtin_bit_cast(bf16x8, aHi[mi]),
                    __builtin_bit_cast(bf16x8, bLo[ni]), acc[mi][ni], 0, 0, 0);
            }
    }

    #pragma unroll
    for (int mi = 0; mi < 2; ++mi)
        #pragma unroll
        for (int r = 0; r < 4; ++r) {
            int node = nodeBase + mi * 16 + quad * 4 + r;
            if (node < N) {
                #pragma unroll
                for (int ni = 0; ni < 2; ++ni) {
                    int c = (wv * 2 + ni) * 16 + m16;
                    Yb[(size_t)node * H_DIM + c] = f2bf_rne(acc[mi][ni][r]);
                }
            }
        }
}

// ---------------------------------------------------------------------------
// Layer-2 GEMM: bf16 A (exact, 16B loads, 2 MFMAs) -> bf16 out.
__global__ __launch_bounds__(256) void gemm_mfma_bf16A(const unsigned short* __restrict__ Xb,
                                                       const unsigned short* __restrict__ WtHi,
                                                       const unsigned short* __restrict__ WtLo,
                                                       unsigned short* __restrict__ Yb, int N) {
    int lane = threadIdx.x & 63;
    int wv   = threadIdx.x >> 6;
    int m16  = lane & 15;
    int quad = lane >> 4;
    int nodeBase = blockIdx.x * 32;

    f32x4 acc[2][2] = {};

    #pragma unroll
    for (int kt = 0; kt < 4; ++kt) {
        int k0 = kt * 32 + quad * 8;

        ushort8 a[2];
        #pragma unroll
        for (int mi = 0; mi < 2; ++mi) {
            int node = nodeBase + mi * 16 + m16;
            if (node >= N) node = N - 1;
            a[mi] = *(const ushort8*)(Xb + (size_t)node * H_DIM + k0);
        }

        ushort8 bHi[2], bLo[2];
        #pragma unroll
        for (int ni = 0; ni < 2; ++ni) {
            int n = (wv * 2 + ni) * 16 + m16;
            size_t off = (size_t)n * H_DIM + k0;
            bHi[ni] = *(const ushort8*)(WtHi + off);
            bLo[ni] = *(const ushort8*)(WtLo + off);
        }

        #pragma unroll
        for (int mi = 0; mi < 2; ++mi)
            #pragma unroll
            for (int ni = 0; ni < 2; ++ni) {
                acc[mi][ni] = __builtin_amdgcn_mfma_f32_16x16x32_bf16(
                    __builtin_bit_cast(bf16x8, a[mi]),
                    __builtin_bit_cast(bf16x8, bHi[ni]), acc[mi][ni], 0, 0, 0);
                acc[mi][ni] = __builtin_amdgcn_mfma_f32_16x16x32_bf16(
                    __builtin_bit_cast(bf16x8, a[mi]),
                    __builtin_bit_cast(bf16x8, bLo[ni]), acc[mi][ni], 0, 0, 0);
            }
    }

    #pragma unroll
    for (int mi = 0; mi < 2; ++mi)
        #pragma unroll
        for (int r = 0; r < 4; ++r) {
            int node = nodeBase + mi * 16 + quad * 4 + r;
            if (node < N) {
                #pragma unroll
                for (int ni = 0; ni < 2; ++ni) {
                    int c = (wv * 2 + ni) * 16 + m16;
                    Yb[(size_t)node * H_DIM + c] = f2bf_rne(acc[mi][ni][r]);
                }
            }
        }
}

// ---------------------------------------------------------------------------
// One wave per destination node, bf16 gather, 4-way unrolled with 4
// independent accumulator pairs (4 gathers in flight, split FMA chains).
__global__ __launch_bounds__(256) void agg_fused(const unsigned short* __restrict__ XWb,
                                                 const float* __restrict__ dinv,
                                                 const int2* __restrict__ csr,
                                                 const int* __restrict__ offs,
                                                 const float* __restrict__ bias,
                                                 unsigned short* __restrict__ OUTb, int N) {
    int wave = (blockIdx.x * 256 + threadIdx.x) >> 6;
    int lane = threadIdx.x & 63;
    if (wave >= N) return;
    int c = wave;
    int start = offs[c], end = offs[c + 1];
    float dc = dinv[c];
    const unsigned int* XW32 = (const unsigned int*)XWb;

    float ax0, ay0;
    {   // self loop
        unsigned int u = XW32[(size_t)c * 64 + lane];
        float s = dc * dc;
        ax0 = bf_lo(u) * s; ay0 = bf_hi(u) * s;
    }
    float ax1 = 0.f, ay1 = 0.f, ax2 = 0.f, ay2 = 0.f, ax3 = 0.f, ay3 = 0.f;

    int i = start;
    for (; i + 3 < end; i += 4) {
        int2 p0 = csr[i];
        int2 p1 = csr[i + 1];
        int2 p2 = csr[i + 2];
        int2 p3 = csr[i + 3];
        unsigned int g0 = XW32[(size_t)p0.x * 64 + lane];
        unsigned int g1 = XW32[(size_t)p1.x * 64 + lane];
        unsigned int g2 = XW32[(size_t)p2.x * 64 + lane];
        unsigned int g3 = XW32[(size_t)p3.x * 64 + lane];
        float n0 = __int_as_float(p0.y);
        float n1 = __int_as_float(p1.y);
        float n2 = __int_as_float(p2.y);
        float n3 = __int_as_float(p3.y);
        ax0 += bf_lo(g0) * n0; ay0 += bf_hi(g0) * n0;
        ax1 += bf_lo(g1) * n1; ay1 += bf_hi(g1) * n1;
        ax2 += bf_lo(g2) * n2; ay2 += bf_hi(g2) * n2;
        ax3 += bf_lo(g3) * n3; ay3 += bf_hi(g3) * n3;
    }
    for (; i < end; ++i) {
        int2 p = csr[i];
        unsigned int g = XW32[(size_t)p.x * 64 + lane];
        float nrm = __int_as_float(p.y);
        ax1 += bf_lo(g) * nrm; ay1 += bf_hi(g) * nrm;
    }
    float ax = (ax0 + ax1) + (ax2 + ax3);
    float ay = (ay0 + ay1) + (ay2 + ay3);
    float2 b = ((const float2*)bias)[lane];
    ax = fmaxf(ax + b.x, 0.f);
    ay = fmaxf(ay + b.y, 0.f);
    unsigned int o = (unsigned int)f2bf_rne(ax) | ((unsigned int)f2bf_rne(ay) << 16);
    ((unsigned int*)(OUTb + (size_t)c * H_DIM))[lane] = o;
}

// ---------------------------------------------------------------------------
// Pooling phase 1: partial sums, atomics flushed per graph-boundary crossing.
__global__ __launch_bounds__(256) void pool_partial(const unsigned short* __restrict__ Hb,
                                                    const int* __restrict__ batch,
                                                    float* __restrict__ pooledSum, int N) {
    __shared__ int sb[64];
    int base = blockIdx.x * 64;
    int t = threadIdx.x;
    if (t < 64) {
        int idx = base + t;
        sb[t] = (idx < N) ? batch[idx] : -1;
    }
    __syncthreads();
    int f   = t & 127;
    int sub = t >> 7;            // 0..1
    int n0  = sub * 32;
    float acc = 0.f;
    int curg = -1;
    #pragma unroll 4
    for (int i = 0; i < 32; ++i) {
        int n = base + n0 + i;
        if (n >= N) break;
        int g = sb[n0 + i];
        if (g != curg) {
            if (curg >= 0) atomicAdd(&pooledSum[curg * H_DIM + f], acc);
            acc = 0.f; curg = g;
        }
        acc += __uint_as_float(((unsigned int)Hb[(size_t)n * H_DIM + f]) << 16);
    }
    if (curg >= 0) atomicAdd(&pooledSum[curg * H_DIM + f], acc);
}

// ---------------------------------------------------------------------------
// Head: count via binary search on sorted batch, mean, FC, log-softmax.
__global__ __launch_bounds__(64) void head_kernel(const float* __restrict__ pooledSum,
                                                  const int* __restrict__ batch,
                                                  const float* __restrict__ Wfc,
                                                  const float* __restrict__ bfc,
                                                  float* __restrict__ out, int N) {
    __shared__ float sl[OUT_DIM + 2];
    __shared__ int bounds[2];
    int g = blockIdx.x;
    int j = threadIdx.x;
    if (j < 2) {
        int v = g + j;
        int lo = 0, hi = N;
        while (lo < hi) {
            int mid = (lo + hi) >> 1;
            if (batch[mid] < v) lo = mid + 1; else hi = mid;
        }
        bounds[j] = lo;
    }
    __syncthreads();
    int cnt = bounds[1] - bounds[0];
    float inv = 1.0f / (float)(cnt > 0 ? cnt : 1);
    if (j < OUT_DIM) {
        float acc = 0.f;
        const float* p = pooledSum + g * H_DIM;
        for (int k = 0; k < H_DIM; ++k) acc += p[k] * Wfc[k * OUT_DIM + j];
        sl[j] = acc * inv + bfc[j];
    }
    __syncthreads();
    if (j == 0) {
        float m = sl[0];
        for (int i = 1; i < OUT_DIM; ++i) m = fmaxf(m, sl[i]);
        float s = 0.f;
        for (int i = 0; i < OUT_DIM; ++i) s += expf(sl[i] - m);
        sl[OUT_DIM] = m + logf(s);
    }
    __syncthreads();
    if (j < OUT_DIM) out[g * OUT_DIM + j] = sl[j] - sl[OUT_DIM];
}

// ---------------------------------------------------------------------------
extern "C" void kernel_launch(void* const* d_in, const int* in_sizes, int n_in,
                              void* d_out, int out_size, void* d_ws, size_t ws_size,
                              hipStream_t stream) {
    const float* x     = (const float*)d_in[0];
    const int*   ei    = (const int*)  d_in[1];
    const int*   batch = (const int*)  d_in[2];
    const float* W1    = (const float*)d_in[3];
    const float* b1    = (const float*)d_in[4];
    const float* W2    = (const float*)d_in[5];
    const float* b2    = (const float*)d_in[6];
    const float* Wfc   = (const float*)d_in[7];
    const float* bfc   = (const float*)d_in[8];
    float* out = (float*)d_out;

    int N = in_sizes[2];
    int E = in_sizes[1] / 2;
    int G = out_size / OUT_DIM;
    const int* row = ei;
    const int* col = ei + E;

    // Workspace layout:
    // cnt[N] | offs[N+1] | cursor[N] | dinv[N] (nAlign each) | csr[E] int2
    //   | Xb[N*128] ushort | Hb[N*128] ushort | pooledSum[G*128] f32
    //   | blockSums[256] | blockOffs[256] | Wt{1,2}{Hi,Lo}[128*128] ushort
    //   | Xhi[N*128] ushort | Xlo[N*128] ushort
    char* wsb = (char*)d_ws;
    size_t nAlign = (size_t)((N + 256) / 256) * 256;   // >= N+1
    int*   cnt    = (int*)wsb;
    int*   offs   = cnt + nAlign;
    int*   cursor = offs + nAlign;
    float* dinv   = (float*)(cursor + nAlign);
    int2*  csr    = (int2*)(dinv + nAlign);
    unsigned short* Xb = (unsigned short*)(csr + E);
    unsigned short* Hb = Xb + (size_t)N * H_DIM;
    float* pooledSum = (float*)(Hb + (size_t)N * H_DIM);
    int* blockSums = (int*)(pooledSum + (size_t)G * H_DIM);
    int* blockOffs = blockSums + 256;
    unsigned short* Wt1Hi = (unsigned short*)(blockOffs + 256);
    unsigned short* Wt1Lo = Wt1Hi + H_DIM * H_DIM;
    unsigned short* Wt2Hi = Wt1Lo + H_DIM * H_DIM;
    unsigned short* Wt2Lo = Wt2Hi + H_DIM * H_DIM;
    unsigned short* Xhi = Wt2Lo + H_DIM * H_DIM;
    unsigned short* Xlo = Xhi + (size_t)N * H_DIM;

    int scanBlocks = (N + 1023) / 1024;   // 40 for N=40000 (<=256 supported)
    int total8 = N * H_DIM / 8;

    // ---- W split/transpose + X split for MFMA
    wconvert<<<128, 256, 0, stream>>>(W1, W2, Wt1Hi, Wt1Lo, Wt2Hi, Wt2Lo);
    xsplit<<<(total8 + 255) / 256, 256, 0, stream>>>(x, Xhi, Xlo, total8);

    // ---- Build dinv + CSR (by destination col)
    hipMemsetAsync(cnt, 0, N * sizeof(int), stream);
    hist_kernel<<<(E + 255) / 256, 256, 0, stream>>>(col, cnt, E);
    dinv_kernel<<<(N + 255) / 256, 256, 0, stream>>>(cnt, dinv, N);
    scan_phase1<<<scanBlocks, 256, 0, stream>>>(cnt, blockSums, N);
    scan_phase2<<<1, 256, 0, stream>>>(blockSums, blockOffs, offs, scanBlocks, N);
    scan_phase3<<<scanBlocks, 256, 0, stream>>>(cnt, blockOffs, offs, cursor, N);
    scatter_kernel<<<(E + 255) / 256, 256, 0, stream>>>(row, col, dinv, cursor, csr, E);

    int aggBlocks  = (N + 3) / 4;     // 4 waves/block, 1 wave/node
    int gemmBlocks = (N + 31) / 32;   // 32 nodes/block

    // ---- Layer 1
    gemm_mfma_splitA<<<gemmBlocks, 256, 0, stream>>>(Xhi, Xlo, Wt1Hi, Wt1Lo, Xb, N);
    agg_fused<<<aggBlocks, 256, 0, stream>>>(Xb, dinv, csr, offs, b1, Hb, N);

    // ---- Layer 2 (reuse Xb for XW2)
    gemm_mfma_bf16A<<<gemmBlocks, 256, 0, stream>>>(Hb, Wt2Hi, Wt2Lo, Xb, N);
    agg_fused<<<aggBlocks, 256, 0, stream>>>(Xb, dinv, csr, offs, b2, Hb, N);

    // ---- Pool (partial sums + atomics) + head (count/divide folded in)
    hipMemsetAsync(pooledSum, 0, (size_t)G * H_DIM * sizeof(float), stream);
    pool_partial<<<(N + 63) / 64, 256, 0, stream>>>(Hb, batch, pooledSum, N);
    head_kernel<<<G, 64, 0, stream>>>(pooledSum, batch, Wfc, bfc, out, N);
}

// Round 8
// 273.558 us; speedup vs baseline: 5.0262x; 1.0594x over previous
//
#include <hip/hip_runtime.h>
#include <math.h>

#define H_DIM 128
#define OUT_DIM 10

typedef __attribute__((ext_vector_type(8))) __bf16 bf16x8;
typedef __attribute__((ext_vector_type(8))) unsigned short ushort8;
typedef __attribute__((ext_vector_type(4))) float f32x4;

__device__ inline unsigned short f2bf_rne(float f) {
    unsigned int u = __float_as_uint(f);
    unsigned int r = u + 0x7FFFu + ((u >> 16) & 1u);
    return (unsigned short)(r >> 16);
}
__device__ inline float bf_lo(unsigned int u) { return __uint_as_float(u << 16); }
__device__ inline float bf_hi(unsigned int u) { return __uint_as_float(u & 0xFFFF0000u); }

// ---------------------------------------------------------------------------
__global__ __launch_bounds__(256) void hist_kernel(const int* __restrict__ col,
                                                   int* __restrict__ cnt, int E) {
    int e = blockIdx.x * 256 + threadIdx.x;
    if (e < E) atomicAdd(&cnt[col[e]], 1);
}

// ---------------------------------------------------------------------------
// Hierarchical scan.  Phase1 also computes dinv (reads cnt anyway).
__global__ __launch_bounds__(256) void scan_phase1(const int* __restrict__ cnt,
                                                   int* __restrict__ blockSums,
                                                   float* __restrict__ dinv, int N) {
    __shared__ int red[256];
    int base = blockIdx.x * 1024;
    int t = threadIdx.x;
    int s = 0;
    for (int i = 0; i < 4; ++i) {
        int idx = base + t * 4 + i;
        if (idx < N) {
            int cv = cnt[idx];
            s += cv;
            dinv[idx] = rsqrtf((float)cv + 1.0f);   // deg>=1 (self loop)
        }
    }
    red[t] = s;
    __syncthreads();
    for (int d = 128; d > 0; d >>= 1) {
        if (t < d) red[t] += red[t + d];
        __syncthreads();
    }
    if (t == 0) blockSums[blockIdx.x] = red[0];
}

__global__ __launch_bounds__(256) void scan_phase2(const int* __restrict__ blockSums,
                                                   int* __restrict__ blockOffs,
                                                   int* __restrict__ offs, int B, int N) {
    __shared__ int sh[256];
    int t = threadIdx.x;
    sh[t] = (t < B) ? blockSums[t] : 0;
    __syncthreads();
    for (int d = 1; d < 256; d <<= 1) {
        int v = (t >= d) ? sh[t - d] : 0;
        __syncthreads();
        sh[t] += v;
        __syncthreads();
    }
    if (t < B) blockOffs[t] = (t == 0) ? 0 : sh[t - 1];
    if (t == 255) offs[N] = sh[255];   // == E
}

__global__ __launch_bounds__(256) void scan_phase3(const int* __restrict__ cnt,
                                                   const int* __restrict__ blockOffs,
                                                   int* __restrict__ offs,
                                                   int* __restrict__ cursor, int N) {
    __shared__ int red[256];
    int base = blockIdx.x * 1024;
    int t = threadIdx.x;
    int v[4];
    int s = 0;
    for (int i = 0; i < 4; ++i) {
        int idx = base + t * 4 + i;
        v[i] = (idx < N) ? cnt[idx] : 0;
        s += v[i];
    }
    red[t] = s;
    __syncthreads();
    for (int d = 1; d < 256; d <<= 1) {   // inclusive Hillis-Steele
        int x = (t >= d) ? red[t - d] : 0;
        __syncthreads();
        red[t] += x;
        __syncthreads();
    }
    int run = blockOffs[blockIdx.x] + ((t == 0) ? 0 : red[t - 1]);
    for (int i = 0; i < 4; ++i) {
        int idx = base + t * 4 + i;
        if (idx < N) { offs[idx] = run; cursor[idx] = run; run += v[i]; }
    }
}

// ---------------------------------------------------------------------------
__global__ __launch_bounds__(256) void scatter_kernel(const int* __restrict__ row,
                                                      const int* __restrict__ col,
                                                      const float* __restrict__ dinv,
                                                      int* __restrict__ cursor,
                                                      int2* __restrict__ csr, int E) {
    int e = blockIdx.x * 256 + threadIdx.x;
    if (e >= E) return;
    int r = row[e], c = col[e];
    int pos = atomicAdd(&cursor[c], 1);
    int2 p; p.x = r; p.y = __float_as_int(dinv[r] * dinv[c]);
    csr[pos] = p;
}

// ---------------------------------------------------------------------------
// Split W (fp32 [k][n]) into transposed bf16 hi/lo planes [n][k].
__global__ __launch_bounds__(256) void wconvert(const float* __restrict__ W1,
                                                const float* __restrict__ W2,
                                                unsigned short* __restrict__ Wt1Hi,
                                                unsigned short* __restrict__ Wt1Lo,
                                                unsigned short* __restrict__ Wt2Hi,
                                                unsigned short* __restrict__ Wt2Lo) {
    int i = blockIdx.x * 256 + threadIdx.x;   // 0..32767
    const float* src       = (i < 16384) ? W1    : W2;
    unsigned short* dh     = (i < 16384) ? Wt1Hi : Wt2Hi;
    unsigned short* dl     = (i < 16384) ? Wt1Lo : Wt2Lo;
    int idx = i & 16383;
    int k = idx >> 7, n = idx & 127;
    float v = src[idx];                        // W[k][n]
    unsigned short hb = f2bf_rne(v);
    float hf = __uint_as_float((unsigned int)hb << 16);
    unsigned short lb = f2bf_rne(v - hf);
    dh[n * H_DIM + k] = hb;
    dl[n * H_DIM + k] = lb;
}

// ---------------------------------------------------------------------------
// Split X (fp32, row-major [N,128]) into bf16 hi/lo planes (same layout).
__global__ __launch_bounds__(256) void xsplit(const float* __restrict__ X,
                                              unsigned short* __restrict__ Xhi,
                                              unsigned short* __restrict__ Xlo,
                                              int total8) {
    int i = blockIdx.x * 256 + threadIdx.x;
    if (i >= total8) return;
    const float* p = X + (size_t)i * 8;
    f32x4 a = *(const f32x4*)p;
    f32x4 b = *(const f32x4*)(p + 4);
    float v[8] = {a.x, a.y, a.z, a.w, b.x, b.y, b.z, b.w};
    ushort8 h, l;
    #pragma unroll
    for (int j = 0; j < 8; ++j) {
        unsigned short hb = f2bf_rne(v[j]);
        float hf = __uint_as_float((unsigned int)hb << 16);
        h[j] = hb;
        l[j] = f2bf_rne(v[j] - hf);
    }
    *(ushort8*)(Xhi + (size_t)i * 8) = h;
    *(ushort8*)(Xlo + (size_t)i * 8) = l;
}

// ---------------------------------------------------------------------------
// Layer-1 GEMM: pre-split bf16 A planes (hi/lo), 3 MFMAs/tile -> bf16 out.
// Layouts: A[m=lane&15][k=quad*8+j]  B[k=quad*8+j][n=lane&15]  D[row=quad*4+r][col=lane&15]
__global__ __launch_bounds__(256) void gemm_mfma_splitA(const unsigned short* __restrict__ Ahi,
                                                        const unsigned short* __restrict__ Alo,
                                                        const unsigned short* __restrict__ WtHi,
                                                        const unsigned short* __restrict__ WtLo,
                                                        unsigned short* __restrict__ Yb, int N) {
    int lane = threadIdx.x & 63;
    int wv   = threadIdx.x >> 6;
    int m16  = lane & 15;
    int quad = lane >> 4;
    int nodeBase = blockIdx.x * 32;

    f32x4 acc[2][2] = {};

    #pragma unroll
    for (int kt = 0; kt < 4; ++kt) {
        int k0 = kt * 32 + quad * 8;

        ushort8 aHi[2], aLo[2];
        #pragma unroll
        for (int mi = 0; mi < 2; ++mi) {
            int node = nodeBase + mi * 16 + m16;
            if (node >= N) node = N - 1;
            size_t off = (size_t)node * H_DIM + k0;
            aHi[mi] = *(const ushort8*)(Ahi + off);
            aLo[mi] = *(const ushort8*)(Alo + off);
        }

        ushort8 bHi[2], bLo[2];
        #pragma unroll
        for (int ni = 0; ni < 2; ++ni) {
            int n = (wv * 2 + ni) * 16 + m16;
            size_t off = (size_t)n * H_DIM + k0;
            bHi[ni] = *(const ushort8*)(WtHi + off);
            bLo[ni] = *(const ushort8*)(WtLo + off);
        }

        #pragma unroll
        for (int mi = 0; mi < 2; ++mi)
            #pragma unroll
            for (int ni = 0; ni < 2; ++ni) {
                acc[mi][ni] = __builtin_amdgcn_mfma_f32_16x16x32_bf16(
                    __builtin_bit_cast(bf16x8, aHi[mi]),
                    __builtin_bit_cast(bf16x8, bHi[ni]), acc[mi][ni], 0, 0, 0);
                acc[mi][ni] = __builtin_amdgcn_mfma_f32_16x16x32_bf16(
                    __builtin_bit_cast(bf16x8, aLo[mi]),
                    __builtin_bit_cast(bf16x8, bHi[ni]), acc[mi][ni], 0, 0, 0);
                acc[mi][ni] = __builtin_amdgcn_mfma_f32_16x16x32_bf16(
                    __builtin_bit_cast(bf16x8, aHi[mi]),
                    __builtin_bit_cast(bf16x8, bLo[ni]), acc[mi][ni], 0, 0, 0);
            }
    }

    #pragma unroll
    for (int mi = 0; mi < 2; ++mi)
        #pragma unroll
        for (int r = 0; r < 4; ++r) {
            int node = nodeBase + mi * 16 + quad * 4 + r;
            if (node < N) {
                #pragma unroll
                for (int ni = 0; ni < 2; ++ni) {
                    int c = (wv * 2 + ni) * 16 + m16;
                    Yb[(size_t)node * H_DIM + c] = f2bf_rne(acc[mi][ni][r]);
                }
            }
        }
}

// ---------------------------------------------------------------------------
// Layer-2 GEMM: bf16 A (exact, 16B loads, 2 MFMAs) -> bf16 out.
__global__ __launch_bounds__(256) void gemm_mfma_bf16A(const unsigned short* __restrict__ Xb,
                                                       const unsigned short* __restrict__ WtHi,
                                                       const unsigned short* __restrict__ WtLo,
                                                       unsigned short* __restrict__ Yb, int N) {
    int lane = threadIdx.x & 63;
    int wv   = threadIdx.x >> 6;
    int m16  = lane & 15;
    int quad = lane >> 4;
    int nodeBase = blockIdx.x * 32;

    f32x4 acc[2][2] = {};

    #pragma unroll
    for (int kt = 0; kt < 4; ++kt) {
        int k0 = kt * 32 + quad * 8;

        ushort8 a[2];
        #pragma unroll
        for (int mi = 0; mi < 2; ++mi) {
            int node = nodeBase + mi * 16 + m16;
            if (node >= N) node = N - 1;
            a[mi] = *(const ushort8*)(Xb + (size_t)node * H_DIM + k0);
        }

        ushort8 bHi[2], bLo[2];
        #pragma unroll
        for (int ni = 0; ni < 2; ++ni) {
            int n = (wv * 2 + ni) * 16 + m16;
            size_t off = (size_t)n * H_DIM + k0;
            bHi[ni] = *(const ushort8*)(WtHi + off);
            bLo[ni] = *(const ushort8*)(WtLo + off);
        }

        #pragma unroll
        for (int mi = 0; mi < 2; ++mi)
            #pragma unroll
            for (int ni = 0; ni < 2; ++ni) {
                acc[mi][ni] = __builtin_amdgcn_mfma_f32_16x16x32_bf16(
                    __builtin_bit_cast(bf16x8, a[mi]),
                    __builtin_bit_cast(bf16x8, bHi[ni]), acc[mi][ni], 0, 0, 0);
                acc[mi][ni] = __builtin_amdgcn_mfma_f32_16x16x32_bf16(
                    __builtin_bit_cast(bf16x8, a[mi]),
                    __builtin_bit_cast(bf16x8, bLo[ni]), acc[mi][ni], 0, 0, 0);
            }
    }

    #pragma unroll
    for (int mi = 0; mi < 2; ++mi)
        #pragma unroll
        for (int r = 0; r < 4; ++r) {
            int node = nodeBase + mi * 16 + quad * 4 + r;
            if (node < N) {
                #pragma unroll
                for (int ni = 0; ni < 2; ++ni) {
                    int c = (wv * 2 + ni) * 16 + m16;
                    Yb[(size_t)node * H_DIM + c] = f2bf_rne(acc[mi][ni][r]);
                }
            }
        }
}

// ---------------------------------------------------------------------------
// One wave per destination node.  Cooperative csr staging: 64 lanes load up
// to 64 segment entries in ONE coalesced 8B/lane load, then __shfl-broadcast
// each entry -> gather addresses available immediately, gathers pipelined.
__global__ __launch_bounds__(256) void agg_fused(const unsigned short* __restrict__ XWb,
                                                 const float* __restrict__ dinv,
                                                 const int2* __restrict__ csr,
                                                 const int* __restrict__ offs,
                                                 const float* __restrict__ bias,
                                                 unsigned short* __restrict__ OUTb, int N) {
    int wave = (blockIdx.x * 256 + threadIdx.x) >> 6;
    int lane = threadIdx.x & 63;
    if (wave >= N) return;
    int c = wave;
    int start = offs[c], end = offs[c + 1];
    float dc = dinv[c];
    const unsigned int* XW32 = (const unsigned int*)XWb;

    float ax0, ay0;
    {   // self loop
        unsigned int u = XW32[(size_t)c * 64 + lane];
        float s = dc * dc;
        ax0 = bf_lo(u) * s; ay0 = bf_hi(u) * s;
    }
    float ax1 = 0.f, ay1 = 0.f, ax2 = 0.f, ay2 = 0.f, ax3 = 0.f, ay3 = 0.f;

    for (int base = start; base < end; base += 64) {
        int m = end - base; if (m > 64) m = 64;
        int2 ce; ce.x = 0; ce.y = 0;
        if (lane < m) ce = csr[base + lane];          // coalesced segment stage

        int j = 0;
        for (; j + 3 < m; j += 4) {
            int r0 = __shfl(ce.x, j);     int b0 = __shfl(ce.y, j);
            int r1 = __shfl(ce.x, j + 1); int b1 = __shfl(ce.y, j + 1);
            int r2 = __shfl(ce.x, j + 2); int b2 = __shfl(ce.y, j + 2);
            int r3 = __shfl(ce.x, j + 3); int b3 = __shfl(ce.y, j + 3);
            unsigned int g0 = XW32[(size_t)r0 * 64 + lane];
            unsigned int g1 = XW32[(size_t)r1 * 64 + lane];
            unsigned int g2 = XW32[(size_t)r2 * 64 + lane];
            unsigned int g3 = XW32[(size_t)r3 * 64 + lane];
            float n0 = __int_as_float(b0);
            float n1 = __int_as_float(b1);
            float n2 = __int_as_float(b2);
            float n3 = __int_as_float(b3);
            ax0 += bf_lo(g0) * n0; ay0 += bf_hi(g0) * n0;
            ax1 += bf_lo(g1) * n1; ay1 += bf_hi(g1) * n1;
            ax2 += bf_lo(g2) * n2; ay2 += bf_hi(g2) * n2;
            ax3 += bf_lo(g3) * n3; ay3 += bf_hi(g3) * n3;
        }
        for (; j < m; ++j) {
            int r = __shfl(ce.x, j); int b = __shfl(ce.y, j);
            unsigned int g = XW32[(size_t)r * 64 + lane];
            float nrm = __int_as_float(b);
            ax1 += bf_lo(g) * nrm; ay1 += bf_hi(g) * nrm;
        }
    }
    float ax = (ax0 + ax1) + (ax2 + ax3);
    float ay = (ay0 + ay1) + (ay2 + ay3);
    float2 b = ((const float2*)bias)[lane];
    ax = fmaxf(ax + b.x, 0.f);
    ay = fmaxf(ay + b.y, 0.f);
    unsigned int o = (unsigned int)f2bf_rne(ax) | ((unsigned int)f2bf_rne(ay) << 16);
    ((unsigned int*)(OUTb + (size_t)c * H_DIM))[lane] = o;
}

// ---------------------------------------------------------------------------
// Pooling phase 1: partial sums, atomics flushed per graph-boundary crossing.
__global__ __launch_bounds__(256) void pool_partial(const unsigned short* __restrict__ Hb,
                                                    const int* __restrict__ batch,
                                                    float* __restrict__ pooledSum, int N) {
    __shared__ int sb[64];
    int base = blockIdx.x * 64;
    int t = threadIdx.x;
    if (t < 64) {
        int idx = base + t;
        sb[t] = (idx < N) ? batch[idx] : -1;
    }
    __syncthreads();
    int f   = t & 127;
    int sub = t >> 7;            // 0..1
    int n0  = sub * 32;
    float acc = 0.f;
    int curg = -1;
    #pragma unroll 4
    for (int i = 0; i < 32; ++i) {
        int n = base + n0 + i;
        if (n >= N) break;
        int g = sb[n0 + i];
        if (g != curg) {
            if (curg >= 0) atomicAdd(&pooledSum[curg * H_DIM + f], acc);
            acc = 0.f; curg = g;
        }
        acc += __uint_as_float(((unsigned int)Hb[(size_t)n * H_DIM + f]) << 16);
    }
    if (curg >= 0) atomicAdd(&pooledSum[curg * H_DIM + f], acc);
}

// ---------------------------------------------------------------------------
// Head: count via binary search on sorted batch, mean, FC, log-softmax.
__global__ __launch_bounds__(64) void head_kernel(const float* __restrict__ pooledSum,
                                                  const int* __restrict__ batch,
                                                  const float* __restrict__ Wfc,
                                                  const float* __restrict__ bfc,
                                                  float* __restrict__ out, int N) {
    __shared__ float sl[OUT_DIM + 2];
    __shared__ int bounds[2];
    int g = blockIdx.x;
    int j = threadIdx.x;
    if (j < 2) {
        int v = g + j;
        int lo = 0, hi = N;
        while (lo < hi) {
            int mid = (lo + hi) >> 1;
            if (batch[mid] < v) lo = mid + 1; else hi = mid;
        }
        bounds[j] = lo;
    }
    __syncthreads();
    int cnt = bounds[1] - bounds[0];
    float inv = 1.0f / (float)(cnt > 0 ? cnt : 1);
    if (j < OUT_DIM) {
        float acc = 0.f;
        const float* p = pooledSum + g * H_DIM;
        for (int k = 0; k < H_DIM; ++k) acc += p[k] * Wfc[k * OUT_DIM + j];
        sl[j] = acc * inv + bfc[j];
    }
    __syncthreads();
    if (j == 0) {
        float m = sl[0];
        for (int i = 1; i < OUT_DIM; ++i) m = fmaxf(m, sl[i]);
        float s = 0.f;
        for (int i = 0; i < OUT_DIM; ++i) s += expf(sl[i] - m);
        sl[OUT_DIM] = m + logf(s);
    }
    __syncthreads();
    if (j < OUT_DIM) out[g * OUT_DIM + j] = sl[j] - sl[OUT_DIM];
}

// ---------------------------------------------------------------------------
extern "C" void kernel_launch(void* const* d_in, const int* in_sizes, int n_in,
                              void* d_out, int out_size, void* d_ws, size_t ws_size,
                              hipStream_t stream) {
    const float* x     = (const float*)d_in[0];
    const int*   ei    = (const int*)  d_in[1];
    const int*   batch = (const int*)  d_in[2];
    const float* W1    = (const float*)d_in[3];
    const float* b1    = (const float*)d_in[4];
    const float* W2    = (const float*)d_in[5];
    const float* b2    = (const float*)d_in[6];
    const float* Wfc   = (const float*)d_in[7];
    const float* bfc   = (const float*)d_in[8];
    float* out = (float*)d_out;

    int N = in_sizes[2];
    int E = in_sizes[1] / 2;
    int G = out_size / OUT_DIM;
    const int* row = ei;
    const int* col = ei + E;

    // Workspace layout:
    // cnt[N] | offs[N+1] | cursor[N] | dinv[N] (nAlign each) | csr[E] int2
    //   | Xb[N*128] ushort | Hb[N*128] ushort | pooledSum[G*128] f32
    //   | blockSums[256] | blockOffs[256] | Wt{1,2}{Hi,Lo}[128*128] ushort
    //   | Xhi[N*128] ushort | Xlo[N*128] ushort
    char* wsb = (char*)d_ws;
    size_t nAlign = (size_t)((N + 256) / 256) * 256;   // >= N+1
    int*   cnt    = (int*)wsb;
    int*   offs   = cnt + nAlign;
    int*   cursor = offs + nAlign;
    float* dinv   = (float*)(cursor + nAlign);
    int2*  csr    = (int2*)(dinv + nAlign);
    unsigned short* Xb = (unsigned short*)(csr + E);
    unsigned short* Hb = Xb + (size_t)N * H_DIM;
    float* pooledSum = (float*)(Hb + (size_t)N * H_DIM);
    int* blockSums = (int*)(pooledSum + (size_t)G * H_DIM);
    int* blockOffs = blockSums + 256;
    unsigned short* Wt1Hi = (unsigned short*)(blockOffs + 256);
    unsigned short* Wt1Lo = Wt1Hi + H_DIM * H_DIM;
    unsigned short* Wt2Hi = Wt1Lo + H_DIM * H_DIM;
    unsigned short* Wt2Lo = Wt2Hi + H_DIM * H_DIM;
    unsigned short* Xhi = Wt2Lo + H_DIM * H_DIM;
    unsigned short* Xlo = Xhi + (size_t)N * H_DIM;

    int scanBlocks = (N + 1023) / 1024;   // 40 for N=40000 (<=256 supported)
    int total8 = N * H_DIM / 8;

    // ---- W split/transpose + X split for MFMA
    wconvert<<<128, 256, 0, stream>>>(W1, W2, Wt1Hi, Wt1Lo, Wt2Hi, Wt2Lo);
    xsplit<<<(total8 + 255) / 256, 256, 0, stream>>>(x, Xhi, Xlo, total8);

    // ---- Build dinv + CSR (by destination col)
    hipMemsetAsync(cnt, 0, N * sizeof(int), stream);
    hist_kernel<<<(E + 255) / 256, 256, 0, stream>>>(col, cnt, E);
    scan_phase1<<<scanBlocks, 256, 0, stream>>>(cnt, blockSums, dinv, N);
    scan_phase2<<<1, 256, 0, stream>>>(blockSums, blockOffs, offs, scanBlocks, N);
    scan_phase3<<<scanBlocks, 256, 0, stream>>>(cnt, blockOffs, offs, cursor, N);
    scatter_kernel<<<(E + 255) / 256, 256, 0, stream>>>(row, col, dinv, cursor, csr, E);

    int aggBlocks  = (N + 3) / 4;     // 4 waves/block, 1 wave/node
    int gemmBlocks = (N + 31) / 32;   // 32 nodes/block

    // ---- Layer 1
    gemm_mfma_splitA<<<gemmBlocks, 256, 0, stream>>>(Xhi, Xlo, Wt1Hi, Wt1Lo, Xb, N);
    agg_fused<<<aggBlocks, 256, 0, stream>>>(Xb, dinv, csr, offs, b1, Hb, N);

    // ---- Layer 2 (reuse Xb for XW2)
    gemm_mfma_bf16A<<<gemmBlocks, 256, 0, stream>>>(Hb, Wt2Hi, Wt2Lo, Xb, N);
    agg_fused<<<aggBlocks, 256, 0, stream>>>(Xb, dinv, csr, offs, b2, Hb, N);

    // ---- Pool (partial sums + atomics) + head (count/divide folded in)
    hipMemsetAsync(pooledSum, 0, (size_t)G * H_DIM * sizeof(float), stream);
    pool_partial<<<(N + 63) / 64, 256, 0, stream>>>(Hb, batch, pooledSum, N);
    head_kernel<<<G, 64, 0, stream>>>(pooledSum, batch, Wfc, bfc, out, N);
}